// Round 13
// baseline (458.277 us; speedup 1.0000x reference)
//
#include <hip/hip_runtime.h>
#include <hip/hip_bf16.h>

#define BATCH 400
#define NPATCH 196
#define DIM 384
#define RTRI 73920          // 384*385/2
#define NSUP 200
#define OUT_SCORE 0
#define OUT_ADC 125
#define OUT_CLS (125 + BATCH * RTRI)

// ws offsets in floats (total 602880 floats = 2.41 MB)
#define WS_W      0         // 400*196  (holds w^2)
#define WS_SQ     78400     // 400*384
#define WS_RSUM   232000    // 400*384 (atomic; zeroed each launch)
#define WS_RM     385600    // 400*384
#define WS_GM     539200    // 400
#define WS_QPART  539600    // 400*8 (zeroed)
#define WS_DOTS   542800    // 200*200 (atomic; zeroed)
#define WS_PNP    582800    // 40*16 (atomic; zeroed)
#define WS_AD     583440    // 200*40
#define WS_QN     591440    // 200
#define WS_PN     591640    // 40
#define WS_PROTO  591680    // 25*384
#define WS_TSM    601280    // 25*64
#define WS_TOTAL  602880

typedef __attribute__((ext_vector_type(8))) short bf16x8;
typedef __attribute__((ext_vector_type(4))) short short4v;
typedef __attribute__((ext_vector_type(4))) float f32x4;

__device__ __forceinline__ float wave_reduce(float v) {
    #pragma unroll
    for (int o = 32; o; o >>= 1) v += __shfl_down(v, o);
    return v;
}

__device__ __forceinline__ unsigned short f2bf(float f) {
    unsigned int x = __float_as_uint(f);
    x += 0x7FFFu + ((x >> 16) & 1u);    // RNE
    return (unsigned short)(x >> 16);
}

__global__ void k_zero(float* __restrict__ p, int n) {
    int i = blockIdx.x * 256 + threadIdx.x;
    if (i < n) p[i] = 0.f;
}

// k1: cosine weights w (stored squared), cls fp32 copy, sq[d] = diag of scaled Gram
__global__ __launch_bounds__(384) void k_prep(const float* __restrict__ lsn,
                                              float* __restrict__ ws,
                                              float* __restrict__ out) {
    int b = blockIdx.x, tid = threadIdx.x;
    __shared__ float clsL[DIM];
    __shared__ float wL[NPATCH];
    __shared__ float red[6];
    const float* base = lsn + (size_t)b * 197 * DIM;
    float c = base[tid];
    clsL[tid] = c;
    out[OUT_CLS + (size_t)b * DIM + tid] = c;
    float s = wave_reduce(c * c);
    int lane = tid & 63, wv = tid >> 6;
    if (!lane) red[wv] = s;
    __syncthreads();
    float clsn = fmaxf(sqrtf(red[0]+red[1]+red[2]+red[3]+red[4]+red[5]), 1e-8f);
    const float* patch = base + DIM;
    for (int p = wv; p < NPATCH; p += 6) {
        const float* pr = patch + p * DIM;
        float dot = 0.f, nsq = 0.f;
        #pragma unroll
        for (int t = 0; t < 6; t++) {
            float v = pr[lane + 64 * t];
            float cl = clsL[lane + 64 * t];
            dot = fmaf(v, cl, dot);
            nsq = fmaf(v, v, nsq);
        }
        dot = wave_reduce(dot);
        nsq = wave_reduce(nsq);
        if (!lane) {
            float val = dot / (clsn * fmaxf(sqrtf(nsq), 1e-8f));
            wL[p] = val;
            ws[WS_W + b * NPATCH + p] = val * val;   // store w^2 (k_gram folds into B)
        }
    }
    __syncthreads();
    float acc = 0.f;
    for (int m = 0; m < NPATCH; m++) {
        float v = wL[m] * patch[m * DIM + tid];
        acc = fmaf(v, v, acc);
    }
    ws[WS_SQ + b * DIM + tid] = acc * (1.0f / 392.0f);
}

// k2: bf16 MFMA Gram, 64x64 triu blocks (21/batch), single-stage LDS.
// LDS k-major [col][GLDM=232]; whole K staged once, ONE barrier, then
// 7 barrier-free ksteps of b128 frag reads + MFMA.
#define GLDM 232            // m-stride in u16 (224+8): 464B = 29*16 (b128-aligned)
__global__ __launch_bounds__(256) void k_gram(const float* __restrict__ lsn,
                                              float* __restrict__ ws,
                                              float* __restrict__ out) {
    // XCD swizzle: batch b pinned to XCD bx%8 (21 blocks of b share one L2)
    int bx = blockIdx.x;                // 0..8399
    int xcd = bx & 7;
    int slot = bx >> 3;                 // 0..1049
    int t = slot % 21;
    int b = (slot / 21) * 8 + xcd;      // 0..399

    int ti = 0;
    {
        int tt = t;
        while (tt >= 6 - ti) { tt -= 6 - ti; ++ti; }
        t = ti + tt;
    }
    int tj = t;                         // ti<=tj over 6 groups of 64

    __shared__ __align__(16) unsigned short As[64 * GLDM];
    __shared__ __align__(16) unsigned short Bs[64 * GLDM];

    int tid = threadIdx.x;
    int lane = tid & 63, w = tid >> 6;
    int wr = w >> 1, wc = w & 1;        // 2x2 waves, each 32x32
    int dl = lane & 15, ms4 = lane >> 4;

    const float* patch = lsn + (size_t)b * 197 * DIM + DIM;
    const float* wrow = ws + WS_W + b * NPATCH;   // w^2

    // single stage: 2 arrays x 224 m x 16 float4 = 7168 tasks / 256 thr = 28
    #pragma unroll
    for (int it = 0; it < 28; ++it) {
        int task = it * 256 + tid;
        int arr = (task >= 3584) ? 1 : 0;
        int tin = arr ? task - 3584 : task;
        int m = tin >> 4;               // 0..223
        int c4 = (tin & 15) << 2;       // 0..60
        float4 v = make_float4(0.f, 0.f, 0.f, 0.f);
        if (m < NPATCH) {
            v = *(const float4*)&patch[(size_t)m * DIM + (arr ? tj : ti) * 64 + c4];
            if (arr) {
                float w2 = wrow[m];
                v.x *= w2; v.y *= w2; v.z *= w2; v.w *= w2;
            }
        }
        unsigned short* dst = arr ? Bs : As;
        float va[4] = {v.x, v.y, v.z, v.w};
        #pragma unroll
        for (int j = 0; j < 4; ++j)
            dst[(c4 + j) * GLDM + m] = f2bf(va[j]);
    }
    __syncthreads();

    f32x4 acc[2][2] = {};
    for (int ks = 0; ks < 7; ++ks) {
        bf16x8 af[2], bfv[2];
        #pragma unroll
        for (int tr = 0; tr < 2; ++tr)
            af[tr] = *(const bf16x8*)&As[(wr * 32 + tr * 16 + dl) * GLDM + ks * 32 + ms4 * 8];
        #pragma unroll
        for (int tc = 0; tc < 2; ++tc)
            bfv[tc] = *(const bf16x8*)&Bs[(wc * 32 + tc * 16 + dl) * GLDM + ks * 32 + ms4 * 8];
        #pragma unroll
        for (int tr = 0; tr < 2; ++tr)
            #pragma unroll
            for (int tc = 0; tc < 2; ++tc)
                acc[tr][tc] = __builtin_amdgcn_mfma_f32_16x16x32_bf16(
                    af[tr], bfv[tc], acc[tr][tc], 0, 0, 0);
    }

    // epilogue (semantics verified r5/r8-r12)
    const float* sqb = ws + WS_SQ + b * DIM;
    int rbase = ti * 64 + wr * 32;
    int cbase = tj * 64 + wc * 32;
    float sqi[2][4], sqj[2];
    #pragma unroll
    for (int tr = 0; tr < 2; ++tr)
        #pragma unroll
        for (int rg = 0; rg < 4; ++rg)
            sqi[tr][rg] = sqb[rbase + tr * 16 + ms4 * 4 + rg];
    #pragma unroll
    for (int tc = 0; tc < 2; ++tc)
        sqj[tc] = sqb[cbase + tc * 16 + dl];

    float* adc = out + OUT_ADC + (size_t)b * RTRI;
    float rs[2][4] = {};
    float cs[2] = {0.f, 0.f};
    #pragma unroll
    for (int tr = 0; tr < 2; ++tr) {
        #pragma unroll
        for (int tc = 0; tc < 2; ++tc) {
            #pragma unroll
            for (int rg = 0; rg < 4; ++rg) {
                int gi = rbase + tr * 16 + ms4 * 4 + rg;
                int gj = cbase + tc * 16 + dl;
                float dc = sqi[tr][rg] + sqj[tc] - acc[tr][tc][rg] * (1.0f / 196.0f);
                if (gi == gj) dc = 0.f;
                dc = fmaxf(dc, 0.f) + 1e-5f;
                float val = __expf(0.4f * __logf(dc));
                rs[tr][rg] += val;
                cs[tc] += val;
                if (gj >= gi)
                    adc[gi * (769 - gi) / 2 + (gj - gi)] = val;
            }
        }
    }
    #pragma unroll
    for (int tr = 0; tr < 2; ++tr)
        #pragma unroll
        for (int rg = 0; rg < 4; ++rg) {
            float vv = rs[tr][rg];
            vv += __shfl_xor(vv, 1); vv += __shfl_xor(vv, 2);
            vv += __shfl_xor(vv, 4); vv += __shfl_xor(vv, 8);
            rs[tr][rg] = vv;
        }
    if ((lane & 15) == 0) {
        #pragma unroll
        for (int tr = 0; tr < 2; ++tr)
            #pragma unroll
            for (int rg = 0; rg < 4; ++rg)
                atomicAdd(&ws[WS_RSUM + b * DIM + rbase + tr * 16 + ms4 * 4 + rg],
                          rs[tr][rg]);
    }
    if (ti != tj) {
        #pragma unroll
        for (int tc = 0; tc < 2; ++tc) {
            float vv = cs[tc];
            vv += __shfl_xor(vv, 16); vv += __shfl_xor(vv, 32);
            cs[tc] = vv;
        }
        if (lane < 16) {
            #pragma unroll
            for (int tc = 0; tc < 2; ++tc)
                atomicAdd(&ws[WS_RSUM + b * DIM + cbase + tc * 16 + lane], cs[tc]);
        }
    }
}

// k3: row means + grand mean
__global__ __launch_bounds__(384) void k_rowmean(float* __restrict__ ws) {
    int b = blockIdx.x, i = threadIdx.x;
    float s = ws[WS_RSUM + b * DIM + i];
    ws[WS_RM + b * DIM + i] = s * (1.0f / 384.0f);
    __shared__ float red[6];
    float tsum = wave_reduce(s);
    int lane = i & 63, wv = i >> 6;
    if (!lane) red[wv] = tsum;
    __syncthreads();
    if (i == 0) {
        float tot = red[0]+red[1]+red[2]+red[3]+red[4]+red[5];
        ws[WS_GM + b] = tot * (1.0f / (384.0f * 384.0f));
    }
}

// k4: in-place centering of adc (fp32), row-walk, + qnorm^2 partials
__global__ __launch_bounds__(256) void k_center(float* __restrict__ ws,
                                                float* __restrict__ out) {
    int s = blockIdx.x;       // row class i % 4 (load balance)
    int b = blockIdx.y;
    int tid = threadIdx.x;
    __shared__ float rmL[DIM];
    __shared__ float redL[4];
    const float* rm = ws + WS_RM + b * DIM;
    rmL[tid] = rm[tid];
    if (tid < DIM - 256) rmL[256 + tid] = rm[256 + tid];
    float gm = ws[WS_GM + b];
    __syncthreads();
    float* adc = out + OUT_ADC + (size_t)b * RTRI;
    float acc = 0.f;
    for (int i = s; i < DIM; i += 4) {
        int base = i * (769 - i) / 2;
        int L = DIM - i;
        float rmi = rmL[i] - gm;
        for (int off = tid; off < L; off += 256) {
            float v = adc[base + off];
            float nv = v - rmi - rmL[i + off];
            adc[base + off] = nv;
            acc = fmaf(nv, nv, acc);
        }
    }
    float t = wave_reduce(acc);
    if (!(tid & 63)) redL[tid >> 6] = t;
    __syncthreads();
    if (!tid) ws[WS_QPART + b * 8 + s] = redL[0] + redL[1] + redL[2] + redL[3];
}

// k5: DOTS[r][c] = dot(query r, ctx c) via split-K bf16 MFMA.
// grid (2,2,NS2): 104x104 output quadrant (padded 128x128), 8 waves (2x4).
#define DKD 32              // K per step
#define LDK 40              // LDS stride in bf16 (80 B: 2-way max aliasing)
#define NS2 105
#define CHB 22              // chunks per block: 105*22*32 = 73920
__global__ __launch_bounds__(512) void k_dots(const float* __restrict__ out,
                                              float* __restrict__ ws) {
    int qi = blockIdx.x, qj = blockIdx.y, ns = blockIdx.z;
    int tid = threadIdx.x;
    int lane = tid & 63, w = tid >> 6;
    int wr = w >> 2, wc = w & 3;        // 2x4 waves: 64 rows x 32 cols each
    __shared__ __align__(16) unsigned short As[128 * LDK];
    __shared__ __align__(16) unsigned short Bs[128 * LDK];
    const float* adc = out + OUT_ADC;
    int realA = (qi == 0) ? 104 : 96;
    int realB = (qj == 0) ? 104 : 96;
    const float* qb = adc + (size_t)(NSUP + qi * 104) * RTRI;
    const float* cb = adc + (size_t)(qj * 104) * RTRI;

    f32x4 acc[4][2] = {};
    for (int ck = 0; ck < CHB; ++ck) {
        int k0 = (ns * CHB + ck) * DKD;
        #pragma unroll
        for (int it = 0; it < 4; ++it) {
            int idx = tid + it * 512;
            int arr = idx >> 10;
            int r = (idx >> 3) & 127;
            int kq = (idx & 7) << 2;
            const float* src = arr ? cb : qb;
            int real = arr ? realB : realA;
            float4 v = make_float4(0.f, 0.f, 0.f, 0.f);
            if (r < real) v = *(const float4*)&src[(size_t)r * RTRI + k0 + kq];
            short4v sv;
            sv[0] = (short)f2bf(v.x); sv[1] = (short)f2bf(v.y);
            sv[2] = (short)f2bf(v.z); sv[3] = (short)f2bf(v.w);
            unsigned short* dst = arr ? Bs : As;
            *(short4v*)&dst[r * LDK + kq] = sv;
        }
        __syncthreads();
        int kb = (lane >> 4) * 8;
        bf16x8 af[4], bfv[2];
        #pragma unroll
        for (int tr = 0; tr < 4; ++tr)
            af[tr] = *(const bf16x8*)&As[(wr * 64 + tr * 16 + (lane & 15)) * LDK + kb];
        #pragma unroll
        for (int tc = 0; tc < 2; ++tc)
            bfv[tc] = *(const bf16x8*)&Bs[(wc * 32 + tc * 16 + (lane & 15)) * LDK + kb];
        #pragma unroll
        for (int tr = 0; tr < 4; ++tr)
            #pragma unroll
            for (int tc = 0; tc < 2; ++tc)
                acc[tr][tc] = __builtin_amdgcn_mfma_f32_16x16x32_bf16(
                    af[tr], bfv[tc], acc[tr][tc], 0, 0, 0);
        __syncthreads();
    }
    #pragma unroll
    for (int tr = 0; tr < 4; ++tr)
        #pragma unroll
        for (int tc = 0; tc < 2; ++tc)
            #pragma unroll
            for (int rg = 0; rg < 4; ++rg) {
                int lr = wr * 64 + tr * 16 + (lane >> 4) * 4 + rg;
                int lc = wc * 32 + tc * 16 + (lane & 15);
                if (lr < realA && lc < realB)
                    atomicAdd(&ws[WS_DOTS + (qi * 104 + lr) * 200 + (qj * 104 + lc)],
                              acc[tr][tc][rg]);
            }
}

// k5b: partial within-class ctx pair dots -> PNP[o][15], split-K
__global__ __launch_bounds__(256) void k_pn(const int* __restrict__ labels,
                                            const float* __restrict__ out,
                                            float* __restrict__ ws) {
    int o = blockIdx.x;      // c*8+f
    int sp = blockIdx.y;     // 0..7 K split
    int c = o >> 3, f = o & 7;
    int tid = threadIdx.x;
    __shared__ int rows[5];
    if (tid == 0) {
        int cnt = 0;
        for (int s = 0; s < 25; s++)
            if (labels[s] == c && cnt < 5) rows[cnt++] = s * 8 + f;
    }
    __syncthreads();
    const float* adc = out + OUT_ADC;
    float acc[15] = {};
    int lo = sp * 9240, hi = lo + 9240;
    for (int k = lo + tid; k < hi; k += 256) {
        float v[5];
        #pragma unroll
        for (int a = 0; a < 5; a++) v[a] = adc[(size_t)rows[a] * RTRI + k];
        int idx = 0;
        #pragma unroll
        for (int a = 0; a < 5; a++)
            #pragma unroll
            for (int b2 = a; b2 < 5; b2++) {
                acc[idx] = fmaf(v[a], v[b2], acc[idx]);
                idx++;
            }
    }
    __shared__ float red[15];
    if (tid < 15) red[tid] = 0.f;
    __syncthreads();
    #pragma unroll
    for (int i = 0; i < 15; i++) {
        float t = wave_reduce(acc[i]);
        if (!(tid & 63)) atomicAdd(&red[i], t);
    }
    __syncthreads();
    if (tid < 15) atomicAdd(&ws[WS_PNP + o * 16 + tid], red[tid]);
}

// k6: qn + pn finalize + ad from DOTS/PNP/QPART
__global__ __launch_bounds__(256) void k_post(const int* __restrict__ labels,
                                              float* __restrict__ ws) {
    __shared__ int mem[5][5];
    int tid = threadIdx.x;
    if (tid == 0) {
        int cnt[5] = {0,0,0,0,0};
        for (int s = 0; s < 25; s++) { int c = labels[s]; if (cnt[c] < 5) mem[c][cnt[c]++] = s; }
    }
    __syncthreads();
    for (int r = tid; r < 200; r += 256) {
        float ssum = 0.f;
        #pragma unroll
        for (int k = 0; k < 8; k++) ssum += ws[WS_QPART + (200 + r) * 8 + k];
        ws[WS_QN + r] = fmaxf(sqrtf(fmaxf(ssum, 0.f)), 1e-8f);
    }
    if (tid < 40) {
        float tot = 0.f;
        int idx = 0;
        #pragma unroll
        for (int a = 0; a < 5; a++)
            #pragma unroll
            for (int b2 = a; b2 < 5; b2++) {
                tot += ((a == b2) ? 1.f : 2.f) * ws[WS_PNP + tid * 16 + idx];
                idx++;
            }
        ws[WS_PN + tid] = fmaxf(sqrtf(fmaxf(tot, 0.f)) * 0.2f, 1e-8f);
    }
    __syncthreads();
    for (int idx = tid; idx < 8000; idx += 256) {
        int r = idx / 40, o = idx % 40;
        int c = o >> 3, f = o & 7;
        float s = 0.f;
        #pragma unroll
        for (int a = 0; a < 5; a++)
            s += ws[WS_DOTS + r * 200 + mem[c][a] * 8 + f];
        ws[WS_AD + idx] = s * 0.2f;
    }
}

// k7: proto[q] = mean_f(query cls) + mean_all(support cls)
__global__ __launch_bounds__(384) void k_proto(const float* __restrict__ lsn,
                                               float* __restrict__ ws) {
    int tid = threadIdx.x;
    float tsv = 0.f;
    for (int r = 0; r < 200; r++) tsv += lsn[(size_t)r * 197 * DIM + tid];
    tsv *= (1.0f / 200.0f);
    for (int q = 0; q < 25; q++) {
        float s = 0.f;
        #pragma unroll
        for (int f = 0; f < 8; f++) s += lsn[(size_t)(200 + q * 8 + f) * 197 * DIM + tid];
        ws[WS_PROTO + q * DIM + tid] = s * (1.0f / 8.0f) + tsv;
    }
}

// k8: tsm[q][g] = proto[q] . gen_weight[g]
__global__ __launch_bounds__(64) void k_tsm(const float* __restrict__ gw,
                                            float* __restrict__ ws) {
    int q = blockIdx.x, g = threadIdx.x;
    const float* pr = ws + WS_PROTO + q * DIM;
    const float* gr = gw + g * DIM;
    float s = 0.f;
    for (int d = 0; d < DIM; d++) s = fmaf(pr[d], gr[d], s);
    ws[WS_TSM + q * 64 + g] = s;
}

// k9: final score
__global__ __launch_bounds__(128) void k_score(const float* __restrict__ ws,
                                               float* __restrict__ out) {
    int t = threadIdx.x;
    if (t >= 125) return;
    int q = t / 5, wway = t % 5;
    float s = 0.f;
    for (int f = 0; f < 8; f++) {
        float qn = ws[WS_QN + q * 8 + f];
        for (int g = 0; g < 8; g++) {
            float ad = ws[WS_AD + (q * 8 + f) * 40 + wway * 8 + g];
            float pnv = ws[WS_PN + wway * 8 + g];
            s += (ad / (qn * pnv)) * ws[WS_TSM + q * 64 + f * 8 + g];
        }
    }
    out[OUT_SCORE + t] = s;
}

extern "C" void kernel_launch(void* const* d_in, const int* in_sizes, int n_in,
                              void* d_out, int out_size, void* d_ws, size_t ws_size,
                              hipStream_t stream) {
    const float* lsn = (const float*)d_in[0];
    const float* gw = (const float*)d_in[1];
    const int* labels = (const int*)d_in[2];
    float* ws = (float*)d_ws;
    float* out = (float*)d_out;

    {
        int n = (WS_AD - WS_RSUM);   // RSUM, RM, GM, QPART, DOTS, PNP
        k_zero<<<dim3((n + 255) / 256), dim3(256), 0, stream>>>(ws + WS_RSUM, n);
    }
    k_prep<<<dim3(BATCH), dim3(384), 0, stream>>>(lsn, ws, out);
    k_gram<<<dim3(21 * BATCH), dim3(256), 0, stream>>>(lsn, ws, out);
    k_rowmean<<<dim3(BATCH), dim3(384), 0, stream>>>(ws);
    k_center<<<dim3(4, BATCH), dim3(256), 0, stream>>>(ws, out);
    k_dots<<<dim3(2, 2, NS2), dim3(512), 0, stream>>>(out, ws);
    k_pn<<<dim3(40, 8), dim3(256), 0, stream>>>(labels, out, ws);
    k_post<<<1, dim3(256), 0, stream>>>(labels, ws);
    k_proto<<<1, dim3(384), 0, stream>>>(lsn, ws);
    k_tsm<<<dim3(25), dim3(64), 0, stream>>>(gw, ws);
    k_score<<<1, dim3(128), 0, stream>>>(ws, out);
}

// Round 14
// 370.570 us; speedup vs baseline: 1.2367x; 1.2367x over previous
//
#include <hip/hip_runtime.h>
#include <hip/hip_bf16.h>

#define BATCH 400
#define NPATCH 196
#define DIM 384
#define RTRI 73920          // 384*385/2
#define NSUP 200
#define OUT_SCORE 0
#define OUT_ADC 125
#define OUT_CLS (125 + BATCH * RTRI)

// ws offsets in floats (total 603264 floats = 2.41 MB)
#define WS_W      0         // 400*196  (holds w^2)
#define WS_SQ     78400     // 400*384
#define WS_RSUM   232000    // 400*384 (atomic; zeroed each launch)
#define WS_RM     385600    // 400*384
#define WS_GM     539200    // 400
#define WS_QPART  539600    // 400*8 (zeroed)
#define WS_DOTS   542800    // 200*200 (atomic; zeroed)
#define WS_PNP    582800    // 40*16 (atomic; zeroed)
#define WS_TSV    583440    // 384 (atomic; zeroed)
#define WS_AD     583824    // 200*40
#define WS_QN     591824    // 200
#define WS_PN     592024    // 40
#define WS_PROTO  592064    // 25*384
#define WS_TSM    601664    // 25*64
#define WS_TOTAL  603264

typedef __attribute__((ext_vector_type(8))) short bf16x8;
typedef __attribute__((ext_vector_type(4))) short short4v;
typedef __attribute__((ext_vector_type(4))) float f32x4;

__device__ __forceinline__ float wave_reduce(float v) {
    #pragma unroll
    for (int o = 32; o; o >>= 1) v += __shfl_down(v, o);
    return v;
}

__device__ __forceinline__ float wave_allreduce(float v) {
    #pragma unroll
    for (int o = 1; o < 64; o <<= 1) v += __shfl_xor(v, o);
    return v;
}

__device__ __forceinline__ unsigned short f2bf(float f) {
    unsigned int x = __float_as_uint(f);
    x += 0x7FFFu + ((x >> 16) & 1u);    // RNE
    return (unsigned short)(x >> 16);
}

__global__ void k_zero(float* __restrict__ p, int n) {
    int i = blockIdx.x * 256 + threadIdx.x;
    if (i < n) p[i] = 0.f;
}

// k1: cosine weights w (stored squared), cls fp32 copy, sq[d] fused (single pass)
__global__ __launch_bounds__(384) void k_prep(const float* __restrict__ lsn,
                                              float* __restrict__ ws,
                                              float* __restrict__ out) {
    int b = blockIdx.x, tid = threadIdx.x;
    __shared__ float clsL[DIM];
    __shared__ float red[6];
    __shared__ float sqP[6][DIM];
    const float* base = lsn + (size_t)b * 197 * DIM;
    float c = base[tid];
    clsL[tid] = c;
    out[OUT_CLS + (size_t)b * DIM + tid] = c;
    float s = wave_reduce(c * c);
    int lane = tid & 63, wv = tid >> 6;
    if (!lane) red[wv] = s;
    __syncthreads();
    float clsn = fmaxf(sqrtf(red[0]+red[1]+red[2]+red[3]+red[4]+red[5]), 1e-8f);
    const float* patch = base + DIM;
    float acc6[6] = {0.f, 0.f, 0.f, 0.f, 0.f, 0.f};
    for (int p = wv; p < NPATCH; p += 6) {
        const float* pr = patch + p * DIM;
        float v[6];
        float dot = 0.f, nsq = 0.f;
        #pragma unroll
        for (int t = 0; t < 6; t++) {
            v[t] = pr[lane + 64 * t];
            dot = fmaf(v[t], clsL[lane + 64 * t], dot);
            nsq = fmaf(v[t], v[t], nsq);
        }
        dot = wave_allreduce(dot);
        nsq = wave_allreduce(nsq);
        float w = dot / (clsn * fmaxf(sqrtf(nsq), 1e-8f));
        if (!lane) ws[WS_W + b * NPATCH + p] = w * w;
        #pragma unroll
        for (int t = 0; t < 6; t++) {
            float wv_ = w * v[t];
            acc6[t] = fmaf(wv_, wv_, acc6[t]);
        }
    }
    #pragma unroll
    for (int t = 0; t < 6; t++) sqP[wv][lane + 64 * t] = acc6[t];
    __syncthreads();
    float tot = 0.f;
    #pragma unroll
    for (int w6 = 0; w6 < 6; w6++) tot += sqP[w6][tid];
    ws[WS_SQ + b * DIM + tid] = tot * (1.0f / 392.0f);
}

// k2: bf16 MFMA Gram, 64x64 triu blocks (21/batch), single-stage LDS. (r13, kept)
#define GLDM 232
__global__ __launch_bounds__(256) void k_gram(const float* __restrict__ lsn,
                                              float* __restrict__ ws,
                                              float* __restrict__ out) {
    int bx = blockIdx.x;
    int xcd = bx & 7;
    int slot = bx >> 3;
    int t = slot % 21;
    int b = (slot / 21) * 8 + xcd;

    int ti = 0;
    {
        int tt = t;
        while (tt >= 6 - ti) { tt -= 6 - ti; ++ti; }
        t = ti + tt;
    }
    int tj = t;

    __shared__ __align__(16) unsigned short As[64 * GLDM];
    __shared__ __align__(16) unsigned short Bs[64 * GLDM];

    int tid = threadIdx.x;
    int lane = tid & 63, w = tid >> 6;
    int wr = w >> 1, wc = w & 1;
    int dl = lane & 15, ms4 = lane >> 4;

    const float* patch = lsn + (size_t)b * 197 * DIM + DIM;
    const float* wrow = ws + WS_W + b * NPATCH;

    #pragma unroll
    for (int it = 0; it < 28; ++it) {
        int task = it * 256 + tid;
        int arr = (task >= 3584) ? 1 : 0;
        int tin = arr ? task - 3584 : task;
        int m = tin >> 4;
        int c4 = (tin & 15) << 2;
        float4 v = make_float4(0.f, 0.f, 0.f, 0.f);
        if (m < NPATCH) {
            v = *(const float4*)&patch[(size_t)m * DIM + (arr ? tj : ti) * 64 + c4];
            if (arr) {
                float w2 = wrow[m];
                v.x *= w2; v.y *= w2; v.z *= w2; v.w *= w2;
            }
        }
        unsigned short* dst = arr ? Bs : As;
        float va[4] = {v.x, v.y, v.z, v.w};
        #pragma unroll
        for (int j = 0; j < 4; ++j)
            dst[(c4 + j) * GLDM + m] = f2bf(va[j]);
    }
    __syncthreads();

    f32x4 acc[2][2] = {};
    for (int ks = 0; ks < 7; ++ks) {
        bf16x8 af[2], bfv[2];
        #pragma unroll
        for (int tr = 0; tr < 2; ++tr)
            af[tr] = *(const bf16x8*)&As[(wr * 32 + tr * 16 + dl) * GLDM + ks * 32 + ms4 * 8];
        #pragma unroll
        for (int tc = 0; tc < 2; ++tc)
            bfv[tc] = *(const bf16x8*)&Bs[(wc * 32 + tc * 16 + dl) * GLDM + ks * 32 + ms4 * 8];
        #pragma unroll
        for (int tr = 0; tr < 2; ++tr)
            #pragma unroll
            for (int tc = 0; tc < 2; ++tc)
                acc[tr][tc] = __builtin_amdgcn_mfma_f32_16x16x32_bf16(
                    af[tr], bfv[tc], acc[tr][tc], 0, 0, 0);
    }

    const float* sqb = ws + WS_SQ + b * DIM;
    int rbase = ti * 64 + wr * 32;
    int cbase = tj * 64 + wc * 32;
    float sqi[2][4], sqj[2];
    #pragma unroll
    for (int tr = 0; tr < 2; ++tr)
        #pragma unroll
        for (int rg = 0; rg < 4; ++rg)
            sqi[tr][rg] = sqb[rbase + tr * 16 + ms4 * 4 + rg];
    #pragma unroll
    for (int tc = 0; tc < 2; ++tc)
        sqj[tc] = sqb[cbase + tc * 16 + dl];

    float* adc = out + OUT_ADC + (size_t)b * RTRI;
    float rs[2][4] = {};
    float cs[2] = {0.f, 0.f};
    #pragma unroll
    for (int tr = 0; tr < 2; ++tr) {
        #pragma unroll
        for (int tc = 0; tc < 2; ++tc) {
            #pragma unroll
            for (int rg = 0; rg < 4; ++rg) {
                int gi = rbase + tr * 16 + ms4 * 4 + rg;
                int gj = cbase + tc * 16 + dl;
                float dc = sqi[tr][rg] + sqj[tc] - acc[tr][tc][rg] * (1.0f / 196.0f);
                if (gi == gj) dc = 0.f;
                dc = fmaxf(dc, 0.f) + 1e-5f;
                float val = __expf(0.4f * __logf(dc));
                rs[tr][rg] += val;
                cs[tc] += val;
                if (gj >= gi)
                    adc[gi * (769 - gi) / 2 + (gj - gi)] = val;
            }
        }
    }
    #pragma unroll
    for (int tr = 0; tr < 2; ++tr)
        #pragma unroll
        for (int rg = 0; rg < 4; ++rg) {
            float vv = rs[tr][rg];
            vv += __shfl_xor(vv, 1); vv += __shfl_xor(vv, 2);
            vv += __shfl_xor(vv, 4); vv += __shfl_xor(vv, 8);
            rs[tr][rg] = vv;
        }
    if ((lane & 15) == 0) {
        #pragma unroll
        for (int tr = 0; tr < 2; ++tr)
            #pragma unroll
            for (int rg = 0; rg < 4; ++rg)
                atomicAdd(&ws[WS_RSUM + b * DIM + rbase + tr * 16 + ms4 * 4 + rg],
                          rs[tr][rg]);
    }
    if (ti != tj) {
        #pragma unroll
        for (int tc = 0; tc < 2; ++tc) {
            float vv = cs[tc];
            vv += __shfl_xor(vv, 16); vv += __shfl_xor(vv, 32);
            cs[tc] = vv;
        }
        if (lane < 16) {
            #pragma unroll
            for (int tc = 0; tc < 2; ++tc)
                atomicAdd(&ws[WS_RSUM + b * DIM + cbase + tc * 16 + lane], cs[tc]);
        }
    }
}

// k3: row means + grand mean
__global__ __launch_bounds__(384) void k_rowmean(float* __restrict__ ws) {
    int b = blockIdx.x, i = threadIdx.x;
    float s = ws[WS_RSUM + b * DIM + i];
    ws[WS_RM + b * DIM + i] = s * (1.0f / 384.0f);
    __shared__ float red[6];
    float tsum = wave_reduce(s);
    int lane = i & 63, wv = i >> 6;
    if (!lane) red[wv] = tsum;
    __syncthreads();
    if (i == 0) {
        float tot = red[0]+red[1]+red[2]+red[3]+red[4]+red[5];
        ws[WS_GM + b] = tot * (1.0f / (384.0f * 384.0f));
    }
}

// k4: in-place centering of adc (fp32), wave-per-row, float4 body + align head/tail
__global__ __launch_bounds__(256) void k_center(float* __restrict__ ws,
                                                float* __restrict__ out) {
    int s = blockIdx.x;       // 0..7
    int b = blockIdx.y;
    int tid = threadIdx.x;
    int lane = tid & 63, wv = tid >> 6;
    __shared__ float rmL[DIM];
    __shared__ float redL[4];
    const float* rm = ws + WS_RM + b * DIM;
    rmL[tid] = rm[tid];
    if (tid < DIM - 256) rmL[256 + tid] = rm[256 + tid];
    float gm = ws[WS_GM + b];
    __syncthreads();
    float* adc = out + OUT_ADC + (size_t)b * RTRI;
    float acc = 0.f;
    int slot = s * 4 + wv;               // 0..31
    for (int k = 0; k < 12; ++k) {
        int i = slot + 32 * k;           // 0..383
        int base = i * (769 - i) / 2;
        int L = DIM - i;
        float rmi = rmL[i] - gm;
        int head = (4 - ((125 + base) & 3)) & 3;
        if (head > L) head = L;
        if (lane < head) {
            float v = adc[base + lane];
            float nv = v - rmi - rmL[i + lane];
            adc[base + lane] = nv;
            acc = fmaf(nv, nv, acc);
        }
        int n4 = (L - head) >> 2;
        for (int q = lane; q < n4; q += 64) {
            int off = head + q * 4;
            float4 v = *(float4*)&adc[base + off];
            float nv0 = v.x - rmi - rmL[i + off];
            float nv1 = v.y - rmi - rmL[i + off + 1];
            float nv2 = v.z - rmi - rmL[i + off + 2];
            float nv3 = v.w - rmi - rmL[i + off + 3];
            *(float4*)&adc[base + off] = make_float4(nv0, nv1, nv2, nv3);
            acc = fmaf(nv0, nv0, acc);
            acc = fmaf(nv1, nv1, acc);
            acc = fmaf(nv2, nv2, acc);
            acc = fmaf(nv3, nv3, acc);
        }
        int tl = head + n4 * 4 + lane;
        if (tl < L) {
            float v = adc[base + tl];
            float nv = v - rmi - rmL[i + tl];
            adc[base + tl] = nv;
            acc = fmaf(nv, nv, acc);
        }
    }
    float t = wave_reduce(acc);
    if (!lane) redL[wv] = t;
    __syncthreads();
    if (!tid) ws[WS_QPART + b * 8 + s] = redL[0] + redL[1] + redL[2] + redL[3];
}

// k5: DOTS via split-K bf16 MFMA (r10, kept)
#define DKD 32
#define LDK 40
#define NS2 105
#define CHB 22
__global__ __launch_bounds__(512) void k_dots(const float* __restrict__ out,
                                              float* __restrict__ ws) {
    int qi = blockIdx.x, qj = blockIdx.y, ns = blockIdx.z;
    int tid = threadIdx.x;
    int lane = tid & 63, w = tid >> 6;
    int wr = w >> 2, wc = w & 3;
    __shared__ __align__(16) unsigned short As[128 * LDK];
    __shared__ __align__(16) unsigned short Bs[128 * LDK];
    const float* adc = out + OUT_ADC;
    int realA = (qi == 0) ? 104 : 96;
    int realB = (qj == 0) ? 104 : 96;
    const float* qb = adc + (size_t)(NSUP + qi * 104) * RTRI;
    const float* cb = adc + (size_t)(qj * 104) * RTRI;

    f32x4 acc[4][2] = {};
    for (int ck = 0; ck < CHB; ++ck) {
        int k0 = (ns * CHB + ck) * DKD;
        #pragma unroll
        for (int it = 0; it < 4; ++it) {
            int idx = tid + it * 512;
            int arr = idx >> 10;
            int r = (idx >> 3) & 127;
            int kq = (idx & 7) << 2;
            const float* src = arr ? cb : qb;
            int real = arr ? realB : realA;
            float4 v = make_float4(0.f, 0.f, 0.f, 0.f);
            if (r < real) v = *(const float4*)&src[(size_t)r * RTRI + k0 + kq];
            short4v sv;
            sv[0] = (short)f2bf(v.x); sv[1] = (short)f2bf(v.y);
            sv[2] = (short)f2bf(v.z); sv[3] = (short)f2bf(v.w);
            unsigned short* dst = arr ? Bs : As;
            *(short4v*)&dst[r * LDK + kq] = sv;
        }
        __syncthreads();
        int kb = (lane >> 4) * 8;
        bf16x8 af[4], bfv[2];
        #pragma unroll
        for (int tr = 0; tr < 4; ++tr)
            af[tr] = *(const bf16x8*)&As[(wr * 64 + tr * 16 + (lane & 15)) * LDK + kb];
        #pragma unroll
        for (int tc = 0; tc < 2; ++tc)
            bfv[tc] = *(const bf16x8*)&Bs[(wc * 32 + tc * 16 + (lane & 15)) * LDK + kb];
        #pragma unroll
        for (int tr = 0; tr < 4; ++tr)
            #pragma unroll
            for (int tc = 0; tc < 2; ++tc)
                acc[tr][tc] = __builtin_amdgcn_mfma_f32_16x16x32_bf16(
                    af[tr], bfv[tc], acc[tr][tc], 0, 0, 0);
        __syncthreads();
    }
    #pragma unroll
    for (int tr = 0; tr < 4; ++tr)
        #pragma unroll
        for (int tc = 0; tc < 2; ++tc)
            #pragma unroll
            for (int rg = 0; rg < 4; ++rg) {
                int lr = wr * 64 + tr * 16 + (lane >> 4) * 4 + rg;
                int lc = wc * 32 + tc * 16 + (lane & 15);
                if (lr < realA && lc < realB)
                    atomicAdd(&ws[WS_DOTS + (qi * 104 + lr) * 200 + (qj * 104 + lc)],
                              acc[tr][tc][rg]);
            }
}

// k5b: partial within-class ctx pair dots -> PNP[o][15], split-K
__global__ __launch_bounds__(256) void k_pn(const int* __restrict__ labels,
                                            const float* __restrict__ out,
                                            float* __restrict__ ws) {
    int o = blockIdx.x;
    int sp = blockIdx.y;
    int c = o >> 3, f = o & 7;
    int tid = threadIdx.x;
    __shared__ int rows[5];
    if (tid == 0) {
        int cnt = 0;
        for (int s = 0; s < 25; s++)
            if (labels[s] == c && cnt < 5) rows[cnt++] = s * 8 + f;
    }
    __syncthreads();
    const float* adc = out + OUT_ADC;
    float acc[15] = {};
    int lo = sp * 9240, hi = lo + 9240;
    for (int k = lo + tid; k < hi; k += 256) {
        float v[5];
        #pragma unroll
        for (int a = 0; a < 5; a++) v[a] = adc[(size_t)rows[a] * RTRI + k];
        int idx = 0;
        #pragma unroll
        for (int a = 0; a < 5; a++)
            #pragma unroll
            for (int b2 = a; b2 < 5; b2++) {
                acc[idx] = fmaf(v[a], v[b2], acc[idx]);
                idx++;
            }
    }
    __shared__ float red[15];
    if (tid < 15) red[tid] = 0.f;
    __syncthreads();
    #pragma unroll
    for (int i = 0; i < 15; i++) {
        float t = wave_reduce(acc[i]);
        if (!(tid & 63)) atomicAdd(&red[i], t);
    }
    __syncthreads();
    if (tid < 15) atomicAdd(&ws[WS_PNP + o * 16 + tid], red[tid]);
}

// k6: qn + pn finalize + ad from DOTS/PNP/QPART
__global__ __launch_bounds__(256) void k_post(const int* __restrict__ labels,
                                              float* __restrict__ ws) {
    __shared__ int mem[5][5];
    int tid = threadIdx.x;
    if (tid == 0) {
        int cnt[5] = {0,0,0,0,0};
        for (int s = 0; s < 25; s++) { int c = labels[s]; if (cnt[c] < 5) mem[c][cnt[c]++] = s; }
    }
    __syncthreads();
    for (int r = tid; r < 200; r += 256) {
        float ssum = 0.f;
        #pragma unroll
        for (int k = 0; k < 8; k++) ssum += ws[WS_QPART + (200 + r) * 8 + k];
        ws[WS_QN + r] = fmaxf(sqrtf(fmaxf(ssum, 0.f)), 1e-8f);
    }
    if (tid < 40) {
        float tot = 0.f;
        int idx = 0;
        #pragma unroll
        for (int a = 0; a < 5; a++)
            #pragma unroll
            for (int b2 = a; b2 < 5; b2++) {
                tot += ((a == b2) ? 1.f : 2.f) * ws[WS_PNP + tid * 16 + idx];
                idx++;
            }
        ws[WS_PN + tid] = fmaxf(sqrtf(fmaxf(tot, 0.f)) * 0.2f, 1e-8f);
    }
    __syncthreads();
    for (int idx = tid; idx < 8000; idx += 256) {
        int r = idx / 40, o = idx % 40;
        int c = o >> 3, f = o & 7;
        float s = 0.f;
        #pragma unroll
        for (int a = 0; a < 5; a++)
            s += ws[WS_DOTS + r * 200 + mem[c][a] * 8 + f];
        ws[WS_AD + idx] = s * 0.2f;
    }
}

// k7a: tsv[d] = sum over 200 support cls rows (atomic partials)
__global__ __launch_bounds__(384) void k_tsv(const float* __restrict__ lsn,
                                             float* __restrict__ ws) {
    int r = blockIdx.x;      // 0..24 -> rows 8r..8r+7
    int tid = threadIdx.x;
    float s = 0.f;
    #pragma unroll
    for (int f = 0; f < 8; f++)
        s += lsn[(size_t)(r * 8 + f) * 197 * DIM + tid];
    atomicAdd(&ws[WS_TSV + tid], s);
}

// k7b: proto[q] = mean_f(query cls) + tsv/200
__global__ __launch_bounds__(384) void k_proto(const float* __restrict__ lsn,
                                               float* __restrict__ ws) {
    int q = blockIdx.x;      // 0..24
    int tid = threadIdx.x;
    float s = 0.f;
    #pragma unroll
    for (int f = 0; f < 8; f++)
        s += lsn[(size_t)(200 + q * 8 + f) * 197 * DIM + tid];
    ws[WS_PROTO + q * DIM + tid] = s * (1.0f / 8.0f) + ws[WS_TSV + tid] * (1.0f / 200.0f);
}

// k8: tsm[q][g] = proto[q] . gen_weight[g]
__global__ __launch_bounds__(64) void k_tsm(const float* __restrict__ gw,
                                            float* __restrict__ ws) {
    int q = blockIdx.x, g = threadIdx.x;
    const float* pr = ws + WS_PROTO + q * DIM;
    const float* gr = gw + g * DIM;
    float s = 0.f;
    for (int d = 0; d < DIM; d++) s = fmaf(pr[d], gr[d], s);
    ws[WS_TSM + q * 64 + g] = s;
}

// k9: final score
__global__ __launch_bounds__(128) void k_score(const float* __restrict__ ws,
                                               float* __restrict__ out) {
    int t = threadIdx.x;
    if (t >= 125) return;
    int q = t / 5, wway = t % 5;
    float s = 0.f;
    for (int f = 0; f < 8; f++) {
        float qn = ws[WS_QN + q * 8 + f];
        for (int g = 0; g < 8; g++) {
            float ad = ws[WS_AD + (q * 8 + f) * 40 + wway * 8 + g];
            float pnv = ws[WS_PN + wway * 8 + g];
            s += (ad / (qn * pnv)) * ws[WS_TSM + q * 64 + f * 8 + g];
        }
    }
    out[OUT_SCORE + t] = s;
}

extern "C" void kernel_launch(void* const* d_in, const int* in_sizes, int n_in,
                              void* d_out, int out_size, void* d_ws, size_t ws_size,
                              hipStream_t stream) {
    const float* lsn = (const float*)d_in[0];
    const float* gw = (const float*)d_in[1];
    const int* labels = (const int*)d_in[2];
    float* ws = (float*)d_ws;
    float* out = (float*)d_out;

    {
        int n = (WS_AD - WS_RSUM);   // RSUM, RM, GM, QPART, DOTS, PNP, TSV
        k_zero<<<dim3((n + 255) / 256), dim3(256), 0, stream>>>(ws + WS_RSUM, n);
    }
    k_prep<<<dim3(BATCH), dim3(384), 0, stream>>>(lsn, ws, out);
    k_gram<<<dim3(21 * BATCH), dim3(256), 0, stream>>>(lsn, ws, out);
    k_rowmean<<<dim3(BATCH), dim3(384), 0, stream>>>(ws);
    k_center<<<dim3(8, BATCH), dim3(256), 0, stream>>>(ws, out);
    k_dots<<<dim3(2, 2, NS2), dim3(512), 0, stream>>>(out, ws);
    k_pn<<<dim3(40, 8), dim3(256), 0, stream>>>(labels, out, ws);
    k_tsv<<<dim3(25), dim3(384), 0, stream>>>(lsn, ws);
    k_proto<<<dim3(25), dim3(384), 0, stream>>>(lsn, ws);
    k_post<<<1, dim3(256), 0, stream>>>(labels, ws);
    k_tsm<<<dim3(25), dim3(64), 0, stream>>>(gw, ws);
    k_score<<<1, dim3(128), 0, stream>>>(ws, out);
}

// Round 16
// 369.589 us; speedup vs baseline: 1.2400x; 1.0027x over previous
//
#include <hip/hip_runtime.h>
#include <hip/hip_bf16.h>

#define BATCH 400
#define NPATCH 196
#define DIM 384
#define RTRI 73920          // 384*385/2
#define NSUP 200
#define OUT_SCORE 0
#define OUT_ADC 125
#define OUT_CLS (125 + BATCH * RTRI)

// ws offsets in floats
#define WS_W      0         // 400*196  (holds w^2)
#define WS_SQ     78400     // 400*384
#define WS_RSUM   232000    // 400*384 (atomic; zeroed each launch)
#define WS_RM     385600    // 400*384 (plain-written)
#define WS_GM     539200    // 400     (plain-written)
#define WS_QPART  539600    // 400*8   (plain-written)
#define WS_DOTS   542800    // 200*200 (atomic; zeroed)
#define WS_PNP    582800    // 40*16 (atomic; zeroed)
#define WS_TSV    583440    // 384 (atomic; zeroed)
#define WS_AD     583824    // 200*40
#define WS_QN     591824    // 200
#define WS_PN     592024    // 40
#define WS_PROTO  592064    // 25*384
#define WS_TSM    601664    // 25*64
#define WS_TOTAL  603264

typedef __attribute__((ext_vector_type(8))) short bf16x8;
typedef __attribute__((ext_vector_type(4))) short short4v;
typedef __attribute__((ext_vector_type(4))) float f32x4;

__device__ __forceinline__ float wave_reduce(float v) {
    #pragma unroll
    for (int o = 32; o; o >>= 1) v += __shfl_down(v, o);
    return v;
}

__device__ __forceinline__ float wave_allreduce(float v) {
    #pragma unroll
    for (int o = 1; o < 64; o <<= 1) v += __shfl_xor(v, o);
    return v;
}

// native bf16 conversions (v_cvt_pk_bf16_f32), RNE — bit-identical to prior hand-RNE
__device__ __forceinline__ unsigned short bf1(float x) {
    __hip_bfloat16 h = __float2bfloat16(x);
    unsigned short u;
    __builtin_memcpy(&u, &h, 2);
    return u;
}
__device__ __forceinline__ unsigned int bf2(float x, float y) {
    __hip_bfloat162 h = __float22bfloat162_rn(make_float2(x, y));
    unsigned int u;
    __builtin_memcpy(&u, &h, 4);
    return u;
}

__global__ void k_zero(float* __restrict__ p, int n) {
    int i = blockIdx.x * 256 + threadIdx.x;
    if (i < n) p[i] = 0.f;
}

// k1: cosine weights w (stored squared), cls fp32 copy, sq[d] fused (single pass)
__global__ __launch_bounds__(384) void k_prep(const float* __restrict__ lsn,
                                              float* __restrict__ ws,
                                              float* __restrict__ out) {
    int b = blockIdx.x, tid = threadIdx.x;
    __shared__ float clsL[DIM];
    __shared__ float red[6];
    __shared__ float sqP[6][DIM];
    const float* base = lsn + (size_t)b * 197 * DIM;
    float c = base[tid];
    clsL[tid] = c;
    out[OUT_CLS + (size_t)b * DIM + tid] = c;
    float s = wave_reduce(c * c);
    int lane = tid & 63, wv = tid >> 6;
    if (!lane) red[wv] = s;
    __syncthreads();
    float clsn = fmaxf(sqrtf(red[0]+red[1]+red[2]+red[3]+red[4]+red[5]), 1e-8f);
    const float* patch = base + DIM;
    float acc6[6] = {0.f, 0.f, 0.f, 0.f, 0.f, 0.f};
    for (int p = wv; p < NPATCH; p += 6) {
        const float* pr = patch + p * DIM;
        float v[6];
        float dot = 0.f, nsq = 0.f;
        #pragma unroll
        for (int t = 0; t < 6; t++) {
            v[t] = pr[lane + 64 * t];
            dot = fmaf(v[t], clsL[lane + 64 * t], dot);
            nsq = fmaf(v[t], v[t], nsq);
        }
        dot = wave_allreduce(dot);
        nsq = wave_allreduce(nsq);
        float w = dot / (clsn * fmaxf(sqrtf(nsq), 1e-8f));
        if (!lane) ws[WS_W + b * NPATCH + p] = w * w;
        #pragma unroll
        for (int t = 0; t < 6; t++) {
            float wv_ = w * v[t];
            acc6[t] = fmaf(wv_, wv_, acc6[t]);
        }
    }
    #pragma unroll
    for (int t = 0; t < 6; t++) sqP[wv][lane + 64 * t] = acc6[t];
    __syncthreads();
    float tot = 0.f;
    #pragma unroll
    for (int w6 = 0; w6 < 6; w6++) tot += sqP[w6][tid];
    ws[WS_SQ + b * DIM + tid] = tot * (1.0f / 392.0f);
}

// k2: bf16 MFMA Gram, 64x64 triu blocks (21/batch), single-stage LDS.
#define GLDM 232
__global__ __launch_bounds__(256) void k_gram(const float* __restrict__ lsn,
                                              float* __restrict__ ws,
                                              float* __restrict__ out) {
    int bx = blockIdx.x;
    int xcd = bx & 7;
    int slot = bx >> 3;
    int t = slot % 21;
    int b = (slot / 21) * 8 + xcd;

    int ti = 0;
    {
        int tt = t;
        while (tt >= 6 - ti) { tt -= 6 - ti; ++ti; }
        t = ti + tt;
    }
    int tj = t;

    __shared__ __align__(16) unsigned short As[64 * GLDM];
    __shared__ __align__(16) unsigned short Bs[64 * GLDM];

    int tid = threadIdx.x;
    int lane = tid & 63, w = tid >> 6;
    int wr = w >> 1, wc = w & 1;
    int dl = lane & 15, ms4 = lane >> 4;

    const float* patch = lsn + (size_t)b * 197 * DIM + DIM;
    const float* wrow = ws + WS_W + b * NPATCH;

    #pragma unroll
    for (int it = 0; it < 28; ++it) {
        int task = it * 256 + tid;
        int arr = (task >= 3584) ? 1 : 0;
        int tin = arr ? task - 3584 : task;
        int m = tin >> 4;
        int c4 = (tin & 15) << 2;
        float4 v = make_float4(0.f, 0.f, 0.f, 0.f);
        if (m < NPATCH) {
            v = *(const float4*)&patch[(size_t)m * DIM + (arr ? tj : ti) * 64 + c4];
            if (arr) {
                float w2 = wrow[m];
                v.x *= w2; v.y *= w2; v.z *= w2; v.w *= w2;
            }
        }
        unsigned short* dst = arr ? Bs : As;
        dst[(c4 + 0) * GLDM + m] = bf1(v.x);
        dst[(c4 + 1) * GLDM + m] = bf1(v.y);
        dst[(c4 + 2) * GLDM + m] = bf1(v.z);
        dst[(c4 + 3) * GLDM + m] = bf1(v.w);
    }
    __syncthreads();

    f32x4 acc[2][2] = {};
    for (int ks = 0; ks < 7; ++ks) {
        bf16x8 af[2], bfv[2];
        #pragma unroll
        for (int tr = 0; tr < 2; ++tr)
            af[tr] = *(const bf16x8*)&As[(wr * 32 + tr * 16 + dl) * GLDM + ks * 32 + ms4 * 8];
        #pragma unroll
        for (int tc = 0; tc < 2; ++tc)
            bfv[tc] = *(const bf16x8*)&Bs[(wc * 32 + tc * 16 + dl) * GLDM + ks * 32 + ms4 * 8];
        #pragma unroll
        for (int tr = 0; tr < 2; ++tr)
            #pragma unroll
            for (int tc = 0; tc < 2; ++tc)
                acc[tr][tc] = __builtin_amdgcn_mfma_f32_16x16x32_bf16(
                    af[tr], bfv[tc], acc[tr][tc], 0, 0, 0);
    }

    const float* sqb = ws + WS_SQ + b * DIM;
    int rbase = ti * 64 + wr * 32;
    int cbase = tj * 64 + wc * 32;
    float sqi[2][4], sqj[2];
    #pragma unroll
    for (int tr = 0; tr < 2; ++tr)
        #pragma unroll
        for (int rg = 0; rg < 4; ++rg)
            sqi[tr][rg] = sqb[rbase + tr * 16 + ms4 * 4 + rg];
    #pragma unroll
    for (int tc = 0; tc < 2; ++tc)
        sqj[tc] = sqb[cbase + tc * 16 + dl];

    float* adc = out + OUT_ADC + (size_t)b * RTRI;
    float rs[2][4] = {};
    float cs[2] = {0.f, 0.f};
    #pragma unroll
    for (int tr = 0; tr < 2; ++tr) {
        #pragma unroll
        for (int rg = 0; rg < 4; ++rg) {
            int gi = rbase + tr * 16 + ms4 * 4 + rg;
            int goff = gi * (769 - gi) / 2 - gi;   // hoisted triu base
            float sq_i = sqi[tr][rg];
            float rsv = 0.f;
            #pragma unroll
            for (int tc = 0; tc < 2; ++tc) {
                int gj = cbase + tc * 16 + dl;
                float dc = sq_i + sqj[tc] - acc[tr][tc][rg] * (1.0f / 196.0f);
                if (gi == gj) dc = 0.f;
                dc = fmaxf(dc, 0.f) + 1e-5f;
                float val = __expf(0.4f * __logf(dc));
                rsv += val;
                cs[tc] += val;
                if (gj >= gi)
                    adc[goff + gj] = val;
            }
            rs[tr][rg] = rsv;
        }
    }
    #pragma unroll
    for (int tr = 0; tr < 2; ++tr)
        #pragma unroll
        for (int rg = 0; rg < 4; ++rg) {
            float vv = rs[tr][rg];
            vv += __shfl_xor(vv, 1); vv += __shfl_xor(vv, 2);
            vv += __shfl_xor(vv, 4); vv += __shfl_xor(vv, 8);
            rs[tr][rg] = vv;
        }
    if ((lane & 15) == 0) {
        #pragma unroll
        for (int tr = 0; tr < 2; ++tr)
            #pragma unroll
            for (int rg = 0; rg < 4; ++rg)
                atomicAdd(&ws[WS_RSUM + b * DIM + rbase + tr * 16 + ms4 * 4 + rg],
                          rs[tr][rg]);
    }
    if (ti != tj) {
        #pragma unroll
        for (int tc = 0; tc < 2; ++tc) {
            float vv = cs[tc];
            vv += __shfl_xor(vv, 16); vv += __shfl_xor(vv, 32);
            cs[tc] = vv;
        }
        if (lane < 16) {
            #pragma unroll
            for (int tc = 0; tc < 2; ++tc)
                atomicAdd(&ws[WS_RSUM + b * DIM + cbase + tc * 16 + lane], cs[tc]);
        }
    }
}

// k3: row means + grand mean
__global__ __launch_bounds__(384) void k_rowmean(float* __restrict__ ws) {
    int b = blockIdx.x, i = threadIdx.x;
    float s = ws[WS_RSUM + b * DIM + i];
    ws[WS_RM + b * DIM + i] = s * (1.0f / 384.0f);
    __shared__ float red[6];
    float tsum = wave_reduce(s);
    int lane = i & 63, wv = i >> 6;
    if (!lane) red[wv] = tsum;
    __syncthreads();
    if (i == 0) {
        float tot = red[0]+red[1]+red[2]+red[3]+red[4]+red[5];
        ws[WS_GM + b] = tot * (1.0f / (384.0f * 384.0f));
    }
}

// k4: in-place centering of adc (fp32), wave-per-row, float4 body + align head/tail
__global__ __launch_bounds__(256) void k_center(float* __restrict__ ws,
                                                float* __restrict__ out) {
    int s = blockIdx.x;       // 0..7
    int b = blockIdx.y;
    int tid = threadIdx.x;
    int lane = tid & 63, wv = tid >> 6;
    __shared__ float rmL[DIM];
    __shared__ float redL[4];
    const float* rm = ws + WS_RM + b * DIM;
    rmL[tid] = rm[tid];
    if (tid < DIM - 256) rmL[256 + tid] = rm[256 + tid];
    float gm = ws[WS_GM + b];
    __syncthreads();
    float* adc = out + OUT_ADC + (size_t)b * RTRI;
    float acc = 0.f;
    int slot = s * 4 + wv;               // 0..31
    for (int k = 0; k < 12; ++k) {
        int i = slot + 32 * k;           // 0..383
        int base = i * (769 - i) / 2;
        int L = DIM - i;
        float rmi = rmL[i] - gm;
        int head = (4 - ((125 + base) & 3)) & 3;
        if (head > L) head = L;
        if (lane < head) {
            float v = adc[base + lane];
            float nv = v - rmi - rmL[i + lane];
            adc[base + lane] = nv;
            acc = fmaf(nv, nv, acc);
        }
        int n4 = (L - head) >> 2;
        for (int q = lane; q < n4; q += 64) {
            int off = head + q * 4;
            float4 v = *(float4*)&adc[base + off];
            float nv0 = v.x - rmi - rmL[i + off];
            float nv1 = v.y - rmi - rmL[i + off + 1];
            float nv2 = v.z - rmi - rmL[i + off + 2];
            float nv3 = v.w - rmi - rmL[i + off + 3];
            *(float4*)&adc[base + off] = make_float4(nv0, nv1, nv2, nv3);
            acc = fmaf(nv0, nv0, acc);
            acc = fmaf(nv1, nv1, acc);
            acc = fmaf(nv2, nv2, acc);
            acc = fmaf(nv3, nv3, acc);
        }
        int tl = head + n4 * 4 + lane;
        if (tl < L) {
            float v = adc[base + tl];
            float nv = v - rmi - rmL[i + tl];
            adc[base + tl] = nv;
            acc = fmaf(nv, nv, acc);
        }
    }
    float t = wave_reduce(acc);
    if (!lane) redL[wv] = t;
    __syncthreads();
    if (!tid) ws[WS_QPART + b * 8 + s] = redL[0] + redL[1] + redL[2] + redL[3];
}

// k5: DOTS via split-K bf16 MFMA; staging uses packed cvt (2 VALU / float4)
#define DKD 32
#define LDK 40
#define NS2 105
#define CHB 22
__global__ __launch_bounds__(512) void k_dots(const float* __restrict__ out,
                                              float* __restrict__ ws) {
    int qi = blockIdx.x, qj = blockIdx.y, ns = blockIdx.z;
    int tid = threadIdx.x;
    int lane = tid & 63, w = tid >> 6;
    int wr = w >> 2, wc = w & 3;
    __shared__ __align__(16) unsigned short As[128 * LDK];
    __shared__ __align__(16) unsigned short Bs[128 * LDK];
    const float* adc = out + OUT_ADC;
    int realA = (qi == 0) ? 104 : 96;
    int realB = (qj == 0) ? 104 : 96;
    const float* qb = adc + (size_t)(NSUP + qi * 104) * RTRI;
    const float* cb = adc + (size_t)(qj * 104) * RTRI;

    f32x4 acc[4][2] = {};
    for (int ck = 0; ck < CHB; ++ck) {
        int k0 = (ns * CHB + ck) * DKD;
        #pragma unroll
        for (int it = 0; it < 4; ++it) {
            int idx = tid + it * 512;
            int arr = idx >> 10;
            int r = (idx >> 3) & 127;
            int kq = (idx & 7) << 2;
            const float* src = arr ? cb : qb;
            int real = arr ? realB : realA;
            float4 v = make_float4(0.f, 0.f, 0.f, 0.f);
            if (r < real) v = *(const float4*)&src[(size_t)r * RTRI + k0 + kq];
            uint2 u = make_uint2(bf2(v.x, v.y), bf2(v.z, v.w));
            unsigned short* dst = arr ? Bs : As;
            *(uint2*)&dst[r * LDK + kq] = u;
        }
        __syncthreads();
        int kb = (lane >> 4) * 8;
        bf16x8 af[4], bfv[2];
        #pragma unroll
        for (int tr = 0; tr < 4; ++tr)
            af[tr] = *(const bf16x8*)&As[(wr * 64 + tr * 16 + (lane & 15)) * LDK + kb];
        #pragma unroll
        for (int tc = 0; tc < 2; ++tc)
            bfv[tc] = *(const bf16x8*)&Bs[(wc * 32 + tc * 16 + (lane & 15)) * LDK + kb];
        #pragma unroll
        for (int tr = 0; tr < 4; ++tr)
            #pragma unroll
            for (int tc = 0; tc < 2; ++tc)
                acc[tr][tc] = __builtin_amdgcn_mfma_f32_16x16x32_bf16(
                    af[tr], bfv[tc], acc[tr][tc], 0, 0, 0);
        __syncthreads();
    }
    #pragma unroll
    for (int tr = 0; tr < 4; ++tr)
        #pragma unroll
        for (int tc = 0; tc < 2; ++tc)
            #pragma unroll
            for (int rg = 0; rg < 4; ++rg) {
                int lr = wr * 64 + tr * 16 + (lane >> 4) * 4 + rg;
                int lc = wc * 32 + tc * 16 + (lane & 15);
                if (lr < realA && lc < realB)
                    atomicAdd(&ws[WS_DOTS + (qi * 104 + lr) * 200 + (qj * 104 + lc)],
                              acc[tr][tc][rg]);
            }
}

// k5b: partial within-class ctx pair dots -> PNP[o][15], split-K
__global__ __launch_bounds__(256) void k_pn(const int* __restrict__ labels,
                                            const float* __restrict__ out,
                                            float* __restrict__ ws) {
    int o = blockIdx.x;
    int sp = blockIdx.y;
    int c = o >> 3, f = o & 7;
    int tid = threadIdx.x;
    __shared__ int rows[5];
    if (tid == 0) {
        int cnt = 0;
        for (int s = 0; s < 25; s++)
            if (labels[s] == c && cnt < 5) rows[cnt++] = s * 8 + f;
    }
    __syncthreads();
    const float* adc = out + OUT_ADC;
    float acc[15] = {};
    int lo = sp * 9240, hi = lo + 9240;
    for (int k = lo + tid; k < hi; k += 256) {
        float v[5];
        #pragma unroll
        for (int a = 0; a < 5; a++) v[a] = adc[(size_t)rows[a] * RTRI + k];
        int idx = 0;
        #pragma unroll
        for (int a = 0; a < 5; a++)
            #pragma unroll
            for (int b2 = a; b2 < 5; b2++) {
                acc[idx] = fmaf(v[a], v[b2], acc[idx]);
                idx++;
            }
    }
    __shared__ float red[15];
    if (tid < 15) red[tid] = 0.f;
    __syncthreads();
    #pragma unroll
    for (int i = 0; i < 15; i++) {
        float t = wave_reduce(acc[i]);
        if (!(tid & 63)) atomicAdd(&red[i], t);
    }
    __syncthreads();
    if (tid < 15) atomicAdd(&ws[WS_PNP + o * 16 + tid], red[tid]);
}

// k6: qn + pn finalize + ad from DOTS/PNP/QPART
__global__ __launch_bounds__(256) void k_post(const int* __restrict__ labels,
                                              float* __restrict__ ws) {
    __shared__ int mem[5][5];
    int tid = threadIdx.x;
    if (tid == 0) {
        int cnt[5] = {0,0,0,0,0};
        for (int s = 0; s < 25; s++) { int c = labels[s]; if (cnt[c] < 5) mem[c][cnt[c]++] = s; }
    }
    __syncthreads();
    for (int r = tid; r < 200; r += 256) {
        float ssum = 0.f;
        #pragma unroll
        for (int k = 0; k < 8; k++) ssum += ws[WS_QPART + (200 + r) * 8 + k];
        ws[WS_QN + r] = fmaxf(sqrtf(fmaxf(ssum, 0.f)), 1e-8f);
    }
    if (tid < 40) {
        float tot = 0.f;
        int idx = 0;
        #pragma unroll
        for (int a = 0; a < 5; a++)
            #pragma unroll
            for (int b2 = a; b2 < 5; b2++) {
                tot += ((a == b2) ? 1.f : 2.f) * ws[WS_PNP + tid * 16 + idx];
                idx++;
            }
        ws[WS_PN + tid] = fmaxf(sqrtf(fmaxf(tot, 0.f)) * 0.2f, 1e-8f);
    }
    __syncthreads();
    for (int idx = tid; idx < 8000; idx += 256) {
        int r = idx / 40, o = idx % 40;
        int c = o >> 3, f = o & 7;
        float s = 0.f;
        #pragma unroll
        for (int a = 0; a < 5; a++)
            s += ws[WS_DOTS + r * 200 + mem[c][a] * 8 + f];
        ws[WS_AD + idx] = s * 0.2f;
    }
}

// k7a: tsv[d] = sum over 200 support cls rows (atomic partials)
__global__ __launch_bounds__(384) void k_tsv(const float* __restrict__ lsn,
                                             float* __restrict__ ws) {
    int r = blockIdx.x;
    int tid = threadIdx.x;
    float s = 0.f;
    #pragma unroll
    for (int f = 0; f < 8; f++)
        s += lsn[(size_t)(r * 8 + f) * 197 * DIM + tid];
    atomicAdd(&ws[WS_TSV + tid], s);
}

// k7b: proto[q] = mean_f(query cls) + tsv/200
__global__ __launch_bounds__(384) void k_proto(const float* __restrict__ lsn,
                                               float* __restrict__ ws) {
    int q = blockIdx.x;
    int tid = threadIdx.x;
    float s = 0.f;
    #pragma unroll
    for (int f = 0; f < 8; f++)
        s += lsn[(size_t)(200 + q * 8 + f) * 197 * DIM + tid];
    ws[WS_PROTO + q * DIM + tid] = s * (1.0f / 8.0f) + ws[WS_TSV + tid] * (1.0f / 200.0f);
}

// k8: tsm[q][g] = proto[q] . gen_weight[g]
__global__ __launch_bounds__(64) void k_tsm(const float* __restrict__ gw,
                                            float* __restrict__ ws) {
    int q = blockIdx.x, g = threadIdx.x;
    const float* pr = ws + WS_PROTO + q * DIM;
    const float* gr = gw + g * DIM;
    float s = 0.f;
    for (int d = 0; d < DIM; d++) s = fmaf(pr[d], gr[d], s);
    ws[WS_TSM + q * 64 + g] = s;
}

// k9: final score
__global__ __launch_bounds__(128) void k_score(const float* __restrict__ ws,
                                               float* __restrict__ out) {
    int t = threadIdx.x;
    if (t >= 125) return;
    int q = t / 5, wway = t % 5;
    float s = 0.f;
    for (int f = 0; f < 8; f++) {
        float qn = ws[WS_QN + q * 8 + f];
        for (int g = 0; g < 8; g++) {
            float ad = ws[WS_AD + (q * 8 + f) * 40 + wway * 8 + g];
            float pnv = ws[WS_PN + wway * 8 + g];
            s += (ad / (qn * pnv)) * ws[WS_TSM + q * 64 + f * 8 + g];
        }
    }
    out[OUT_SCORE + t] = s;
}

extern "C" void kernel_launch(void* const* d_in, const int* in_sizes, int n_in,
                              void* d_out, int out_size, void* d_ws, size_t ws_size,
                              hipStream_t stream) {
    const float* lsn = (const float*)d_in[0];
    const float* gw = (const float*)d_in[1];
    const int* labels = (const int*)d_in[2];
    float* ws = (float*)d_ws;
    float* out = (float*)d_out;

    // zero only the accumulated regions: RSUM, and DOTS..AD (DOTS,PNP,TSV)
    {
        int n1 = WS_RM - WS_RSUM;      // 153600
        k_zero<<<dim3((n1 + 255) / 256), dim3(256), 0, stream>>>(ws + WS_RSUM, n1);
        int n2 = WS_AD - WS_DOTS;      // 41024
        k_zero<<<dim3((n2 + 255) / 256), dim3(256), 0, stream>>>(ws + WS_DOTS, n2);
    }
    k_prep<<<dim3(BATCH), dim3(384), 0, stream>>>(lsn, ws, out);
    k_gram<<<dim3(21 * BATCH), dim3(256), 0, stream>>>(lsn, ws, out);
    k_rowmean<<<dim3(BATCH), dim3(384), 0, stream>>>(ws);
    k_center<<<dim3(8, BATCH), dim3(256), 0, stream>>>(ws, out);
    k_dots<<<dim3(2, 2, NS2), dim3(512), 0, stream>>>(out, ws);
    k_pn<<<dim3(40, 8), dim3(256), 0, stream>>>(labels, out, ws);
    k_tsv<<<dim3(25), dim3(384), 0, stream>>>(lsn, ws);
    k_proto<<<dim3(25), dim3(384), 0, stream>>>(lsn, ws);
    k_post<<<1, dim3(256), 0, stream>>>(labels, ws);
    k_tsm<<<dim3(25), dim3(64), 0, stream>>>(gw, ws);
    k_score<<<1, dim3(128), 0, stream>>>(ws, out);
}

// Round 17
// 347.132 us; speedup vs baseline: 1.3202x; 1.0647x over previous
//
#include <hip/hip_runtime.h>
#include <hip/hip_bf16.h>

#define BATCH 400
#define NPATCH 196
#define DIM 384
#define RTRI 73920          // 384*385/2
#define NSUP 200
#define OUT_SCORE 0
#define OUT_ADC 125
#define OUT_CLS (125 + BATCH * RTRI)

// ws offsets in floats
#define WS_W      0         // 400*196  (holds w^2)
#define WS_SQ     78400     // 400*384
#define WS_RSUM   232000    // 400*384 (atomic; zeroed each launch)
#define WS_RM     385600    // 400*384 (plain-written)
#define WS_GM     539200    // 400     (plain-written)
#define WS_QPART  539600    // 400*8   (plain-written)
#define WS_DOTS   542800    // 200*200 (atomic; zeroed)
#define WS_PNP    582800    // 40*16 (atomic; zeroed)
#define WS_TSV    583440    // 384 (atomic; zeroed)
#define WS_AD     583824    // 200*40
#define WS_QN     591824    // 200
#define WS_PN     592024    // 40
#define WS_PROTO  592064    // 25*384
#define WS_TSM    601664    // 25*64
#define WS_TOTAL  603264

typedef __attribute__((ext_vector_type(8))) short bf16x8;
typedef __attribute__((ext_vector_type(4))) short short4v;
typedef __attribute__((ext_vector_type(4))) float f32x4;

__device__ __forceinline__ float wave_reduce(float v) {
    #pragma unroll
    for (int o = 32; o; o >>= 1) v += __shfl_down(v, o);
    return v;
}

__device__ __forceinline__ float wave_allreduce(float v) {
    #pragma unroll
    for (int o = 1; o < 64; o <<= 1) v += __shfl_xor(v, o);
    return v;
}

// native bf16 conversions (v_cvt_pk_bf16_f32), RNE
__device__ __forceinline__ unsigned short bf1(float x) {
    __hip_bfloat16 h = __float2bfloat16(x);
    unsigned short u;
    __builtin_memcpy(&u, &h, 2);
    return u;
}
__device__ __forceinline__ unsigned int bf2(float x, float y) {
    __hip_bfloat162 h = __float22bfloat162_rn(make_float2(x, y));
    unsigned int u;
    __builtin_memcpy(&u, &h, 4);
    return u;
}

__global__ void k_zero(float* __restrict__ p, int n) {
    int i = blockIdx.x * 256 + threadIdx.x;
    if (i < n) p[i] = 0.f;
}

// k1: cosine weights w (stored squared), cls fp32 copy, sq[d] fused (single pass)
__global__ __launch_bounds__(384) void k_prep(const float* __restrict__ lsn,
                                              float* __restrict__ ws,
                                              float* __restrict__ out) {
    int b = blockIdx.x, tid = threadIdx.x;
    __shared__ float clsL[DIM];
    __shared__ float red[6];
    __shared__ float sqP[6][DIM];
    const float* base = lsn + (size_t)b * 197 * DIM;
    float c = base[tid];
    clsL[tid] = c;
    out[OUT_CLS + (size_t)b * DIM + tid] = c;
    float s = wave_reduce(c * c);
    int lane = tid & 63, wv = tid >> 6;
    if (!lane) red[wv] = s;
    __syncthreads();
    float clsn = fmaxf(sqrtf(red[0]+red[1]+red[2]+red[3]+red[4]+red[5]), 1e-8f);
    const float* patch = base + DIM;
    float acc6[6] = {0.f, 0.f, 0.f, 0.f, 0.f, 0.f};
    for (int p = wv; p < NPATCH; p += 6) {
        const float* pr = patch + p * DIM;
        float v[6];
        float dot = 0.f, nsq = 0.f;
        #pragma unroll
        for (int t = 0; t < 6; t++) {
            v[t] = pr[lane + 64 * t];
            dot = fmaf(v[t], clsL[lane + 64 * t], dot);
            nsq = fmaf(v[t], v[t], nsq);
        }
        dot = wave_allreduce(dot);
        nsq = wave_allreduce(nsq);
        float w = dot / (clsn * fmaxf(sqrtf(nsq), 1e-8f));
        if (!lane) ws[WS_W + b * NPATCH + p] = w * w;
        #pragma unroll
        for (int t = 0; t < 6; t++) {
            float wv_ = w * v[t];
            acc6[t] = fmaf(wv_, wv_, acc6[t]);
        }
    }
    #pragma unroll
    for (int t = 0; t < 6; t++) sqP[wv][lane + 64 * t] = acc6[t];
    __syncthreads();
    float tot = 0.f;
    #pragma unroll
    for (int w6 = 0; w6 < 6; w6++) tot += sqP[w6][tid];
    ws[WS_SQ + b * DIM + tid] = tot * (1.0f / 392.0f);
}

// k2: bf16 MFMA Gram, 64x64 triu blocks (21/batch), single-stage LDS.
// LDS k-major [col][GLDM=232] with GRANULE ROTATION: 16B granule g of row col
// stored at g' = (g + (col>>2)) mod 29. Breaks the 8-way write conflict
// (write banks now 8-distinct per 16-lane group) while keeping b128 reads.
#define GLDM 232
__global__ __launch_bounds__(256) void k_gram(const float* __restrict__ lsn,
                                              float* __restrict__ ws,
                                              float* __restrict__ out) {
    int bx = blockIdx.x;
    int xcd = bx & 7;
    int slot = bx >> 3;
    int t = slot % 21;
    int b = (slot / 21) * 8 + xcd;

    int ti = 0;
    {
        int tt = t;
        while (tt >= 6 - ti) { tt -= 6 - ti; ++ti; }
        t = ti + tt;
    }
    int tj = t;

    __shared__ __align__(16) unsigned short As[64 * GLDM];
    __shared__ __align__(16) unsigned short Bs[64 * GLDM];

    int tid = threadIdx.x;
    int lane = tid & 63, w = tid >> 6;
    int wr = w >> 1, wc = w & 1;
    int dl = lane & 15, ms4 = lane >> 4;

    const float* patch = lsn + (size_t)b * 197 * DIM + DIM;
    const float* wrow = ws + WS_W + b * NPATCH;

    #pragma unroll
    for (int it = 0; it < 28; ++it) {
        int task = it * 256 + tid;
        int arr = (task >= 3584) ? 1 : 0;
        int tin = arr ? task - 3584 : task;
        int m = tin >> 4;
        int col2 = tin & 15;            // (c4+j)>>2 for all j in 0..3
        int c4 = col2 << 2;
        float4 v = make_float4(0.f, 0.f, 0.f, 0.f);
        if (m < NPATCH) {
            v = *(const float4*)&patch[(size_t)m * DIM + (arr ? tj : ti) * 64 + c4];
            if (arr) {
                float w2 = wrow[m];
                v.x *= w2; v.y *= w2; v.z *= w2; v.w *= w2;
            }
        }
        int g2 = (m >> 3) + col2;
        if (g2 >= 29) g2 -= 29;         // rotated granule index
        int rowoff = g2 * 8 + (m & 7);
        unsigned short* dst = arr ? Bs : As;
        dst[(c4 + 0) * GLDM + rowoff] = bf1(v.x);
        dst[(c4 + 1) * GLDM + rowoff] = bf1(v.y);
        dst[(c4 + 2) * GLDM + rowoff] = bf1(v.z);
        dst[(c4 + 3) * GLDM + rowoff] = bf1(v.w);
    }
    __syncthreads();

    f32x4 acc[2][2] = {};
    for (int ks = 0; ks < 7; ++ks) {
        bf16x8 af[2], bfv[2];
        #pragma unroll
        for (int tr = 0; tr < 2; ++tr) {
            int colA = wr * 32 + tr * 16 + dl;
            int gg = ks * 4 + ms4 + (colA >> 2);
            if (gg >= 29) gg -= 29;
            af[tr] = *(const bf16x8*)&As[colA * GLDM + gg * 8];
        }
        #pragma unroll
        for (int tc = 0; tc < 2; ++tc) {
            int colB = wc * 32 + tc * 16 + dl;
            int gg = ks * 4 + ms4 + (colB >> 2);
            if (gg >= 29) gg -= 29;
            bfv[tc] = *(const bf16x8*)&Bs[colB * GLDM + gg * 8];
        }
        #pragma unroll
        for (int tr = 0; tr < 2; ++tr)
            #pragma unroll
            for (int tc = 0; tc < 2; ++tc)
                acc[tr][tc] = __builtin_amdgcn_mfma_f32_16x16x32_bf16(
                    af[tr], bfv[tc], acc[tr][tc], 0, 0, 0);
    }

    const float* sqb = ws + WS_SQ + b * DIM;
    int rbase = ti * 64 + wr * 32;
    int cbase = tj * 64 + wc * 32;
    float sqi[2][4], sqj[2];
    #pragma unroll
    for (int tr = 0; tr < 2; ++tr)
        #pragma unroll
        for (int rg = 0; rg < 4; ++rg)
            sqi[tr][rg] = sqb[rbase + tr * 16 + ms4 * 4 + rg];
    #pragma unroll
    for (int tc = 0; tc < 2; ++tc)
        sqj[tc] = sqb[cbase + tc * 16 + dl];

    float* adc = out + OUT_ADC + (size_t)b * RTRI;
    float rs[2][4] = {};
    float cs[2] = {0.f, 0.f};
    #pragma unroll
    for (int tr = 0; tr < 2; ++tr) {
        #pragma unroll
        for (int rg = 0; rg < 4; ++rg) {
            int gi = rbase + tr * 16 + ms4 * 4 + rg;
            int goff = gi * (769 - gi) / 2 - gi;
            float sq_i = sqi[tr][rg];
            float rsv = 0.f;
            #pragma unroll
            for (int tc = 0; tc < 2; ++tc) {
                int gj = cbase + tc * 16 + dl;
                float dc = sq_i + sqj[tc] - acc[tr][tc][rg] * (1.0f / 196.0f);
                if (gi == gj) dc = 0.f;
                dc = fmaxf(dc, 0.f) + 1e-5f;
                float val = __expf(0.4f * __logf(dc));
                rsv += val;
                cs[tc] += val;
                if (gj >= gi)
                    adc[goff + gj] = val;
            }
            rs[tr][rg] = rsv;
        }
    }
    #pragma unroll
    for (int tr = 0; tr < 2; ++tr)
        #pragma unroll
        for (int rg = 0; rg < 4; ++rg) {
            float vv = rs[tr][rg];
            vv += __shfl_xor(vv, 1); vv += __shfl_xor(vv, 2);
            vv += __shfl_xor(vv, 4); vv += __shfl_xor(vv, 8);
            rs[tr][rg] = vv;
        }
    if ((lane & 15) == 0) {
        #pragma unroll
        for (int tr = 0; tr < 2; ++tr)
            #pragma unroll
            for (int rg = 0; rg < 4; ++rg)
                atomicAdd(&ws[WS_RSUM + b * DIM + rbase + tr * 16 + ms4 * 4 + rg],
                          rs[tr][rg]);
    }
    if (ti != tj) {
        #pragma unroll
        for (int tc = 0; tc < 2; ++tc) {
            float vv = cs[tc];
            vv += __shfl_xor(vv, 16); vv += __shfl_xor(vv, 32);
            cs[tc] = vv;
        }
        if (lane < 16) {
            #pragma unroll
            for (int tc = 0; tc < 2; ++tc)
                atomicAdd(&ws[WS_RSUM + b * DIM + cbase + tc * 16 + lane], cs[tc]);
        }
    }
}

// k3: row means + grand mean
__global__ __launch_bounds__(384) void k_rowmean(float* __restrict__ ws) {
    int b = blockIdx.x, i = threadIdx.x;
    float s = ws[WS_RSUM + b * DIM + i];
    ws[WS_RM + b * DIM + i] = s * (1.0f / 384.0f);
    __shared__ float red[6];
    float tsum = wave_reduce(s);
    int lane = i & 63, wv = i >> 6;
    if (!lane) red[wv] = tsum;
    __syncthreads();
    if (i == 0) {
        float tot = red[0]+red[1]+red[2]+red[3]+red[4]+red[5];
        ws[WS_GM + b] = tot * (1.0f / (384.0f * 384.0f));
    }
}

// k4: in-place centering of adc (fp32), wave-per-row, float4 body + align head/tail
__global__ __launch_bounds__(256) void k_center(float* __restrict__ ws,
                                                float* __restrict__ out) {
    int s = blockIdx.x;       // 0..7
    int b = blockIdx.y;
    int tid = threadIdx.x;
    int lane = tid & 63, wv = tid >> 6;
    __shared__ float rmL[DIM];
    __shared__ float redL[4];
    const float* rm = ws + WS_RM + b * DIM;
    rmL[tid] = rm[tid];
    if (tid < DIM - 256) rmL[256 + tid] = rm[256 + tid];
    float gm = ws[WS_GM + b];
    __syncthreads();
    float* adc = out + OUT_ADC + (size_t)b * RTRI;
    float acc = 0.f;
    int slot = s * 4 + wv;               // 0..31
    for (int k = 0; k < 12; ++k) {
        int i = slot + 32 * k;           // 0..383
        int base = i * (769 - i) / 2;
        int L = DIM - i;
        float rmi = rmL[i] - gm;
        int head = (4 - ((125 + base) & 3)) & 3;
        if (head > L) head = L;
        if (lane < head) {
            float v = adc[base + lane];
            float nv = v - rmi - rmL[i + lane];
            adc[base + lane] = nv;
            acc = fmaf(nv, nv, acc);
        }
        int n4 = (L - head) >> 2;
        for (int q = lane; q < n4; q += 64) {
            int off = head + q * 4;
            float4 v = *(float4*)&adc[base + off];
            float nv0 = v.x - rmi - rmL[i + off];
            float nv1 = v.y - rmi - rmL[i + off + 1];
            float nv2 = v.z - rmi - rmL[i + off + 2];
            float nv3 = v.w - rmi - rmL[i + off + 3];
            *(float4*)&adc[base + off] = make_float4(nv0, nv1, nv2, nv3);
            acc = fmaf(nv0, nv0, acc);
            acc = fmaf(nv1, nv1, acc);
            acc = fmaf(nv2, nv2, acc);
            acc = fmaf(nv3, nv3, acc);
        }
        int tl = head + n4 * 4 + lane;
        if (tl < L) {
            float v = adc[base + tl];
            float nv = v - rmi - rmL[i + tl];
            adc[base + tl] = nv;
            acc = fmaf(nv, nv, acc);
        }
    }
    float t = wave_reduce(acc);
    if (!lane) redL[wv] = t;
    __syncthreads();
    if (!tid) ws[WS_QPART + b * 8 + s] = redL[0] + redL[1] + redL[2] + redL[3];
}

// k5: DOTS via split-K bf16 MFMA; staging uses packed cvt
#define DKD 32
#define LDK 40
#define NS2 105
#define CHB 22
__global__ __launch_bounds__(512) void k_dots(const float* __restrict__ out,
                                              float* __restrict__ ws) {
    int qi = blockIdx.x, qj = blockIdx.y, ns = blockIdx.z;
    int tid = threadIdx.x;
    int lane = tid & 63, w = tid >> 6;
    int wr = w >> 2, wc = w & 3;
    __shared__ __align__(16) unsigned short As[128 * LDK];
    __shared__ __align__(16) unsigned short Bs[128 * LDK];
    const float* adc = out + OUT_ADC;
    int realA = (qi == 0) ? 104 : 96;
    int realB = (qj == 0) ? 104 : 96;
    const float* qb = adc + (size_t)(NSUP + qi * 104) * RTRI;
    const float* cb = adc + (size_t)(qj * 104) * RTRI;

    f32x4 acc[4][2] = {};
    for (int ck = 0; ck < CHB; ++ck) {
        int k0 = (ns * CHB + ck) * DKD;
        #pragma unroll
        for (int it = 0; it < 4; ++it) {
            int idx = tid + it * 512;
            int arr = idx >> 10;
            int r = (idx >> 3) & 127;
            int kq = (idx & 7) << 2;
            const float* src = arr ? cb : qb;
            int real = arr ? realB : realA;
            float4 v = make_float4(0.f, 0.f, 0.f, 0.f);
            if (r < real) v = *(const float4*)&src[(size_t)r * RTRI + k0 + kq];
            uint2 u = make_uint2(bf2(v.x, v.y), bf2(v.z, v.w));
            unsigned short* dst = arr ? Bs : As;
            *(uint2*)&dst[r * LDK + kq] = u;
        }
        __syncthreads();
        int kb = (lane >> 4) * 8;
        bf16x8 af[4], bfv[2];
        #pragma unroll
        for (int tr = 0; tr < 4; ++tr)
            af[tr] = *(const bf16x8*)&As[(wr * 64 + tr * 16 + (lane & 15)) * LDK + kb];
        #pragma unroll
        for (int tc = 0; tc < 2; ++tc)
            bfv[tc] = *(const bf16x8*)&Bs[(wc * 32 + tc * 16 + (lane & 15)) * LDK + kb];
        #pragma unroll
        for (int tr = 0; tr < 4; ++tr)
            #pragma unroll
            for (int tc = 0; tc < 2; ++tc)
                acc[tr][tc] = __builtin_amdgcn_mfma_f32_16x16x32_bf16(
                    af[tr], bfv[tc], acc[tr][tc], 0, 0, 0);
        __syncthreads();
    }
    #pragma unroll
    for (int tr = 0; tr < 4; ++tr)
        #pragma unroll
        for (int tc = 0; tc < 2; ++tc)
            #pragma unroll
            for (int rg = 0; rg < 4; ++rg) {
                int lr = wr * 64 + tr * 16 + (lane >> 4) * 4 + rg;
                int lc = wc * 32 + tc * 16 + (lane & 15);
                if (lr < realA && lc < realB)
                    atomicAdd(&ws[WS_DOTS + (qi * 104 + lr) * 200 + (qj * 104 + lc)],
                              acc[tr][tc][rg]);
            }
}

// k5b: partial within-class ctx pair dots -> PNP[o][15], split-K
__global__ __launch_bounds__(256) void k_pn(const int* __restrict__ labels,
                                            const float* __restrict__ out,
                                            float* __restrict__ ws) {
    int o = blockIdx.x;
    int sp = blockIdx.y;
    int c = o >> 3, f = o & 7;
    int tid = threadIdx.x;
    __shared__ int rows[5];
    if (tid == 0) {
        int cnt = 0;
        for (int s = 0; s < 25; s++)
            if (labels[s] == c && cnt < 5) rows[cnt++] = s * 8 + f;
    }
    __syncthreads();
    const float* adc = out + OUT_ADC;
    float acc[15] = {};
    int lo = sp * 9240, hi = lo + 9240;
    for (int k = lo + tid; k < hi; k += 256) {
        float v[5];
        #pragma unroll
        for (int a = 0; a < 5; a++) v[a] = adc[(size_t)rows[a] * RTRI + k];
        int idx = 0;
        #pragma unroll
        for (int a = 0; a < 5; a++)
            #pragma unroll
            for (int b2 = a; b2 < 5; b2++) {
                acc[idx] = fmaf(v[a], v[b2], acc[idx]);
                idx++;
            }
    }
    __shared__ float red[15];
    if (tid < 15) red[tid] = 0.f;
    __syncthreads();
    #pragma unroll
    for (int i = 0; i < 15; i++) {
        float t = wave_reduce(acc[i]);
        if (!(tid & 63)) atomicAdd(&red[i], t);
    }
    __syncthreads();
    if (tid < 15) atomicAdd(&ws[WS_PNP + o * 16 + tid], red[tid]);
}

// k6: qn + pn finalize + ad from DOTS/PNP/QPART
__global__ __launch_bounds__(256) void k_post(const int* __restrict__ labels,
                                              float* __restrict__ ws) {
    __shared__ int mem[5][5];
    int tid = threadIdx.x;
    if (tid == 0) {
        int cnt[5] = {0,0,0,0,0};
        for (int s = 0; s < 25; s++) { int c = labels[s]; if (cnt[c] < 5) mem[c][cnt[c]++] = s; }
    }
    __syncthreads();
    for (int r = tid; r < 200; r += 256) {
        float ssum = 0.f;
        #pragma unroll
        for (int k = 0; k < 8; k++) ssum += ws[WS_QPART + (200 + r) * 8 + k];
        ws[WS_QN + r] = fmaxf(sqrtf(fmaxf(ssum, 0.f)), 1e-8f);
    }
    if (tid < 40) {
        float tot = 0.f;
        int idx = 0;
        #pragma unroll
        for (int a = 0; a < 5; a++)
            #pragma unroll
            for (int b2 = a; b2 < 5; b2++) {
                tot += ((a == b2) ? 1.f : 2.f) * ws[WS_PNP + tid * 16 + idx];
                idx++;
            }
        ws[WS_PN + tid] = fmaxf(sqrtf(fmaxf(tot, 0.f)) * 0.2f, 1e-8f);
    }
    __syncthreads();
    for (int idx = tid; idx < 8000; idx += 256) {
        int r = idx / 40, o = idx % 40;
        int c = o >> 3, f = o & 7;
        float s = 0.f;
        #pragma unroll
        for (int a = 0; a < 5; a++)
            s += ws[WS_DOTS + r * 200 + mem[c][a] * 8 + f];
        ws[WS_AD + idx] = s * 0.2f;
    }
}

// k7a: tsv[d] = sum over 200 support cls rows (atomic partials)
__global__ __launch_bounds__(384) void k_tsv(const float* __restrict__ lsn,
                                             float* __restrict__ ws) {
    int r = blockIdx.x;
    int tid = threadIdx.x;
    float s = 0.f;
    #pragma unroll
    for (int f = 0; f < 8; f++)
        s += lsn[(size_t)(r * 8 + f) * 197 * DIM + tid];
    atomicAdd(&ws[WS_TSV + tid], s);
}

// k7b: proto[q] = mean_f(query cls) + tsv/200
__global__ __launch_bounds__(384) void k_proto(const float* __restrict__ lsn,
                                               float* __restrict__ ws) {
    int q = blockIdx.x;
    int tid = threadIdx.x;
    float s = 0.f;
    #pragma unroll
    for (int f = 0; f < 8; f++)
        s += lsn[(size_t)(200 + q * 8 + f) * 197 * DIM + tid];
    ws[WS_PROTO + q * DIM + tid] = s * (1.0f / 8.0f) + ws[WS_TSV + tid] * (1.0f / 200.0f);
}

// k8: tsm[q][g] = proto[q] . gen_weight[g]
__global__ __launch_bounds__(64) void k_tsm(const float* __restrict__ gw,
                                            float* __restrict__ ws) {
    int q = blockIdx.x, g = threadIdx.x;
    const float* pr = ws + WS_PROTO + q * DIM;
    const float* gr = gw + g * DIM;
    float s = 0.f;
    for (int d = 0; d < DIM; d++) s = fmaf(pr[d], gr[d], s);
    ws[WS_TSM + q * 64 + g] = s;
}

// k9: final score
__global__ __launch_bounds__(128) void k_score(const float* __restrict__ ws,
                                               float* __restrict__ out) {
    int t = threadIdx.x;
    if (t >= 125) return;
    int q = t / 5, wway = t % 5;
    float s = 0.f;
    for (int f = 0; f < 8; f++) {
        float qn = ws[WS_QN + q * 8 + f];
        for (int g = 0; g < 8; g++) {
            float ad = ws[WS_AD + (q * 8 + f) * 40 + wway * 8 + g];
            float pnv = ws[WS_PN + wway * 8 + g];
            s += (ad / (qn * pnv)) * ws[WS_TSM + q * 64 + f * 8 + g];
        }
    }
    out[OUT_SCORE + t] = s;
}

extern "C" void kernel_launch(void* const* d_in, const int* in_sizes, int n_in,
                              void* d_out, int out_size, void* d_ws, size_t ws_size,
                              hipStream_t stream) {
    const float* lsn = (const float*)d_in[0];
    const float* gw = (const float*)d_in[1];
    const int* labels = (const int*)d_in[2];
    float* ws = (float*)d_ws;
    float* out = (float*)d_out;

    // zero only the accumulated regions: RSUM, and DOTS..AD (DOTS,PNP,TSV)
    {
        int n1 = WS_RM - WS_RSUM;      // 153600
        k_zero<<<dim3((n1 + 255) / 256), dim3(256), 0, stream>>>(ws + WS_RSUM, n1);
        int n2 = WS_AD - WS_DOTS;      // 41024
        k_zero<<<dim3((n2 + 255) / 256), dim3(256), 0, stream>>>(ws + WS_DOTS, n2);
    }
    k_prep<<<dim3(BATCH), dim3(384), 0, stream>>>(lsn, ws, out);
    k_gram<<<dim3(21 * BATCH), dim3(256), 0, stream>>>(lsn, ws, out);
    k_rowmean<<<dim3(BATCH), dim3(384), 0, stream>>>(ws);
    k_center<<<dim3(8, BATCH), dim3(256), 0, stream>>>(ws, out);
    k_dots<<<dim3(2, 2, NS2), dim3(512), 0, stream>>>(out, ws);
    k_pn<<<dim3(40, 8), dim3(256), 0, stream>>>(labels, out, ws);
    k_tsv<<<dim3(25), dim3(384), 0, stream>>>(lsn, ws);
    k_proto<<<dim3(25), dim3(384), 0, stream>>>(lsn, ws);
    k_post<<<1, dim3(256), 0, stream>>>(labels, ws);
    k_tsm<<<dim3(25), dim3(64), 0, stream>>>(gw, ws);
    k_score<<<1, dim3(128), 0, stream>>>(ws, out);
}

// Round 18
// 339.608 us; speedup vs baseline: 1.3494x; 1.0222x over previous
//
#include <hip/hip_runtime.h>
#include <hip/hip_bf16.h>

#define BATCH 400
#define NPATCH 196
#define DIM 384
#define RTRI 73920          // 384*385/2
#define NSUP 200
#define OUT_SCORE 0
#define OUT_ADC 125
#define OUT_CLS (125 + BATCH * RTRI)

// ws offsets in floats
#define WS_W      0         // 400*196  (holds w)
#define WS_SQ     78400     // 400*384
#define WS_RSUM   232000    // 400*384 (atomic; zeroed each launch)
#define WS_RM     385600    // 400*384 (plain-written)
#define WS_GM     539200    // 400     (plain-written)
#define WS_QPART  539600    // 400*8   (plain-written)
#define WS_DOTS   542800    // 200*200 (atomic; zeroed)
#define WS_PNP    582800    // 40*16 (atomic; zeroed)
#define WS_TSV    583440    // 384 (atomic; zeroed)
#define WS_AD     583824    // 200*40
#define WS_QN     591824    // 200
#define WS_PN     592024    // 40
#define WS_PROTO  592064    // 25*384
#define WS_TSM    601664    // 25*64
#define WS_TOTAL  603264

typedef __attribute__((ext_vector_type(8))) short bf16x8;
typedef __attribute__((ext_vector_type(4))) short short4v;
typedef __attribute__((ext_vector_type(4))) float f32x4;

__device__ __forceinline__ float wave_reduce(float v) {
    #pragma unroll
    for (int o = 32; o; o >>= 1) v += __shfl_down(v, o);
    return v;
}

__device__ __forceinline__ float wave_allreduce(float v) {
    #pragma unroll
    for (int o = 1; o < 64; o <<= 1) v += __shfl_xor(v, o);
    return v;
}

// native bf16 conversions, RNE
__device__ __forceinline__ unsigned short bf1(float x) {
    __hip_bfloat16 h = __float2bfloat16(x);
    unsigned short u;
    __builtin_memcpy(&u, &h, 2);
    return u;
}
__device__ __forceinline__ unsigned int bf2(float x, float y) {
    __hip_bfloat162 h = __float22bfloat162_rn(make_float2(x, y));
    unsigned int u;
    __builtin_memcpy(&u, &h, 4);
    return u;
}

__global__ void k_zero(float* __restrict__ p, int n) {
    int i = blockIdx.x * 256 + threadIdx.x;
    if (i < n) p[i] = 0.f;
}

// k1: cosine weights w (stored raw), cls fp32 copy, sq[d] fused (single pass)
__global__ __launch_bounds__(384) void k_prep(const float* __restrict__ lsn,
                                              float* __restrict__ ws,
                                              float* __restrict__ out) {
    int b = blockIdx.x, tid = threadIdx.x;
    __shared__ float clsL[DIM];
    __shared__ float red[6];
    __shared__ float sqP[6][DIM];
    const float* base = lsn + (size_t)b * 197 * DIM;
    float c = base[tid];
    clsL[tid] = c;
    out[OUT_CLS + (size_t)b * DIM + tid] = c;
    float s = wave_reduce(c * c);
    int lane = tid & 63, wv = tid >> 6;
    if (!lane) red[wv] = s;
    __syncthreads();
    float clsn = fmaxf(sqrtf(red[0]+red[1]+red[2]+red[3]+red[4]+red[5]), 1e-8f);
    const float* patch = base + DIM;
    float acc6[6] = {0.f, 0.f, 0.f, 0.f, 0.f, 0.f};
    for (int p = wv; p < NPATCH; p += 6) {
        const float* pr = patch + p * DIM;
        float v[6];
        float dot = 0.f, nsq = 0.f;
        #pragma unroll
        for (int t = 0; t < 6; t++) {
            v[t] = pr[lane + 64 * t];
            dot = fmaf(v[t], clsL[lane + 64 * t], dot);
            nsq = fmaf(v[t], v[t], nsq);
        }
        dot = wave_allreduce(dot);
        nsq = wave_allreduce(nsq);
        float w = dot / (clsn * fmaxf(sqrtf(nsq), 1e-8f));
        if (!lane) ws[WS_W + b * NPATCH + p] = w;     // raw w (k_gram scales both sides)
        #pragma unroll
        for (int t = 0; t < 6; t++) {
            float wv_ = w * v[t];
            acc6[t] = fmaf(wv_, wv_, acc6[t]);
        }
    }
    #pragma unroll
    for (int t = 0; t < 6; t++) sqP[wv][lane + 64 * t] = acc6[t];
    __syncthreads();
    float tot = 0.f;
    #pragma unroll
    for (int w6 = 0; w6 < 6; w6++) tot += sqP[w6][tid];
    ws[WS_SQ + b * DIM + tid] = tot * (1.0f / 392.0f);
}

// k2: bf16 MFMA Gram, 64x64 triu blocks, single-stage LDS, granule rotation.
// Both operands scaled by w -> diagonal blocks stage once (Bs aliases As).
// Incremental staging addressing: fixed (col2,mrow)/thread, m += 16.
#define GLDM 232
__global__ __launch_bounds__(256) void k_gram(const float* __restrict__ lsn,
                                              float* __restrict__ ws,
                                              float* __restrict__ out) {
    int bx = blockIdx.x;
    int xcd = bx & 7;
    int slot = bx >> 3;
    int t = slot % 21;
    int b = (slot / 21) * 8 + xcd;

    int ti = 0;
    {
        int tt = t;
        while (tt >= 6 - ti) { tt -= 6 - ti; ++ti; }
        t = ti + tt;
    }
    int tj = t;
    bool diag = (ti == tj);

    __shared__ __align__(16) unsigned short As[64 * GLDM];
    __shared__ __align__(16) unsigned short Bs[64 * GLDM];
    __shared__ float wL[224];

    int tid = threadIdx.x;
    int lane = tid & 63, w = tid >> 6;
    int wr = w >> 1, wc = w & 1;
    int dl = lane & 15, ms4 = lane >> 4;

    const float* patch = lsn + (size_t)b * 197 * DIM + DIM;
    const float* wrow = ws + WS_W + b * NPATCH;

    if (tid < 224) wL[tid] = (tid < NPATCH) ? wrow[tid] : 0.f;
    __syncthreads();

    int col2 = tid & 15;
    int mrow = tid >> 4;
    int c4 = col2 << 2;
    int blow = mrow & 7;
    int ahi = mrow >> 3;

    #pragma unroll
    for (int arr = 0; arr < 2; ++arr) {
        if (arr && diag) break;
        unsigned short* dst = arr ? Bs : As;
        const float* srcbase = patch + (arr ? tj : ti) * 64 + c4;
        int g2 = ahi + col2;            // <= 16 < 29
        #pragma unroll
        for (int itm = 0; itm < 14; ++itm) {
            int m = mrow + itm * 16;
            float4 v = make_float4(0.f, 0.f, 0.f, 0.f);
            if (m < NPATCH) v = *(const float4*)&srcbase[(size_t)m * DIM];
            float wm = wL[m];
            v.x *= wm; v.y *= wm; v.z *= wm; v.w *= wm;
            int rowoff = g2 * 8 + blow;
            dst[(c4 + 0) * GLDM + rowoff] = bf1(v.x);
            dst[(c4 + 1) * GLDM + rowoff] = bf1(v.y);
            dst[(c4 + 2) * GLDM + rowoff] = bf1(v.z);
            dst[(c4 + 3) * GLDM + rowoff] = bf1(v.w);
            g2 += 2;
            if (g2 >= 29) g2 -= 29;
        }
    }
    __syncthreads();

    const unsigned short* Bbase = diag ? As : Bs;
    f32x4 acc[2][2] = {};
    for (int ks = 0; ks < 7; ++ks) {
        bf16x8 af[2], bfv[2];
        #pragma unroll
        for (int tr = 0; tr < 2; ++tr) {
            int colA = wr * 32 + tr * 16 + dl;
            int gg = ks * 4 + ms4 + (colA >> 2);
            if (gg >= 29) gg -= 29;
            af[tr] = *(const bf16x8*)&As[colA * GLDM + gg * 8];
        }
        #pragma unroll
        for (int tc = 0; tc < 2; ++tc) {
            int colB = wc * 32 + tc * 16 + dl;
            int gg = ks * 4 + ms4 + (colB >> 2);
            if (gg >= 29) gg -= 29;
            bfv[tc] = *(const bf16x8*)&Bbase[colB * GLDM + gg * 8];
        }
        #pragma unroll
        for (int tr = 0; tr < 2; ++tr)
            #pragma unroll
            for (int tc = 0; tc < 2; ++tc)
                acc[tr][tc] = __builtin_amdgcn_mfma_f32_16x16x32_bf16(
                    af[tr], bfv[tc], acc[tr][tc], 0, 0, 0);
    }

    const float* sqb = ws + WS_SQ + b * DIM;
    int rbase = ti * 64 + wr * 32;
    int cbase = tj * 64 + wc * 32;
    float sqi[2][4], sqj[2];
    #pragma unroll
    for (int tr = 0; tr < 2; ++tr)
        #pragma unroll
        for (int rg = 0; rg < 4; ++rg)
            sqi[tr][rg] = sqb[rbase + tr * 16 + ms4 * 4 + rg];
    #pragma unroll
    for (int tc = 0; tc < 2; ++tc)
        sqj[tc] = sqb[cbase + tc * 16 + dl];

    float* adc = out + OUT_ADC + (size_t)b * RTRI;
    float rs[2][4] = {};
    float cs[2] = {0.f, 0.f};
    #pragma unroll
    for (int tr = 0; tr < 2; ++tr) {
        #pragma unroll
        for (int rg = 0; rg < 4; ++rg) {
            int gi = rbase + tr * 16 + ms4 * 4 + rg;
            int goff = gi * (769 - gi) / 2 - gi;
            float sq_i = sqi[tr][rg];
            float rsv = 0.f;
            #pragma unroll
            for (int tc = 0; tc < 2; ++tc) {
                int gj = cbase + tc * 16 + dl;
                float dc = sq_i + sqj[tc] - acc[tr][tc][rg] * (1.0f / 196.0f);
                if (gi == gj) dc = 0.f;
                dc = fmaxf(dc, 0.f) + 1e-5f;
                float val = __expf(0.4f * __logf(dc));
                rsv += val;
                cs[tc] += val;
                if (gj >= gi)
                    adc[goff + gj] = val;
            }
            rs[tr][rg] = rsv;
        }
    }
    #pragma unroll
    for (int tr = 0; tr < 2; ++tr)
        #pragma unroll
        for (int rg = 0; rg < 4; ++rg) {
            float vv = rs[tr][rg];
            vv += __shfl_xor(vv, 1); vv += __shfl_xor(vv, 2);
            vv += __shfl_xor(vv, 4); vv += __shfl_xor(vv, 8);
            rs[tr][rg] = vv;
        }
    if ((lane & 15) == 0) {
        #pragma unroll
        for (int tr = 0; tr < 2; ++tr)
            #pragma unroll
            for (int rg = 0; rg < 4; ++rg)
                atomicAdd(&ws[WS_RSUM + b * DIM + rbase + tr * 16 + ms4 * 4 + rg],
                          rs[tr][rg]);
    }
    if (ti != tj) {
        #pragma unroll
        for (int tc = 0; tc < 2; ++tc) {
            float vv = cs[tc];
            vv += __shfl_xor(vv, 16); vv += __shfl_xor(vv, 32);
            cs[tc] = vv;
        }
        if (lane < 16) {
            #pragma unroll
            for (int tc = 0; tc < 2; ++tc)
                atomicAdd(&ws[WS_RSUM + b * DIM + cbase + tc * 16 + lane], cs[tc]);
        }
    }
}

// k3: row means + grand mean
__global__ __launch_bounds__(384) void k_rowmean(float* __restrict__ ws) {
    int b = blockIdx.x, i = threadIdx.x;
    float s = ws[WS_RSUM + b * DIM + i];
    ws[WS_RM + b * DIM + i] = s * (1.0f / 384.0f);
    __shared__ float red[6];
    float tsum = wave_reduce(s);
    int lane = i & 63, wv = i >> 6;
    if (!lane) red[wv] = tsum;
    __syncthreads();
    if (i == 0) {
        float tot = red[0]+red[1]+red[2]+red[3]+red[4]+red[5];
        ws[WS_GM + b] = tot * (1.0f / (384.0f * 384.0f));
    }
}

// k4: in-place centering of adc (fp32), wave-per-row, float4 body + align head/tail
__global__ __launch_bounds__(256) void k_center(float* __restrict__ ws,
                                                float* __restrict__ out) {
    int s = blockIdx.x;       // 0..7
    int b = blockIdx.y;
    int tid = threadIdx.x;
    int lane = tid & 63, wv = tid >> 6;
    __shared__ float rmL[DIM];
    __shared__ float redL[4];
    const float* rm = ws + WS_RM + b * DIM;
    rmL[tid] = rm[tid];
    if (tid < DIM - 256) rmL[256 + tid] = rm[256 + tid];
    float gm = ws[WS_GM + b];
    __syncthreads();
    float* adc = out + OUT_ADC + (size_t)b * RTRI;
    float acc = 0.f;
    int slot = s * 4 + wv;               // 0..31
    for (int k = 0; k < 12; ++k) {
        int i = slot + 32 * k;           // 0..383
        int base = i * (769 - i) / 2;
        int L = DIM - i;
        float rmi = rmL[i] - gm;
        int head = (4 - ((125 + base) & 3)) & 3;
        if (head > L) head = L;
        if (lane < head) {
            float v = adc[base + lane];
            float nv = v - rmi - rmL[i + lane];
            adc[base + lane] = nv;
            acc = fmaf(nv, nv, acc);
        }
        int n4 = (L - head) >> 2;
        for (int q = lane; q < n4; q += 64) {
            int off = head + q * 4;
            float4 v = *(float4*)&adc[base + off];
            float nv0 = v.x - rmi - rmL[i + off];
            float nv1 = v.y - rmi - rmL[i + off + 1];
            float nv2 = v.z - rmi - rmL[i + off + 2];
            float nv3 = v.w - rmi - rmL[i + off + 3];
            *(float4*)&adc[base + off] = make_float4(nv0, nv1, nv2, nv3);
            acc = fmaf(nv0, nv0, acc);
            acc = fmaf(nv1, nv1, acc);
            acc = fmaf(nv2, nv2, acc);
            acc = fmaf(nv3, nv3, acc);
        }
        int tl = head + n4 * 4 + lane;
        if (tl < L) {
            float v = adc[base + tl];
            float nv = v - rmi - rmL[i + tl];
            adc[base + tl] = nv;
            acc = fmaf(nv, nv, acc);
        }
    }
    float t = wave_reduce(acc);
    if (!lane) redL[wv] = t;
    __syncthreads();
    if (!tid) ws[WS_QPART + b * 8 + s] = redL[0] + redL[1] + redL[2] + redL[3];
}

// k5: DOTS via split-K bf16 MFMA; staging uses packed cvt
#define DKD 32
#define LDK 40
#define NS2 105
#define CHB 22
__global__ __launch_bounds__(512) void k_dots(const float* __restrict__ out,
                                              float* __restrict__ ws) {
    int qi = blockIdx.x, qj = blockIdx.y, ns = blockIdx.z;
    int tid = threadIdx.x;
    int lane = tid & 63, w = tid >> 6;
    int wr = w >> 2, wc = w & 3;
    __shared__ __align__(16) unsigned short As[128 * LDK];
    __shared__ __align__(16) unsigned short Bs[128 * LDK];
    const float* adc = out + OUT_ADC;
    int realA = (qi == 0) ? 104 : 96;
    int realB = (qj == 0) ? 104 : 96;
    const float* qb = adc + (size_t)(NSUP + qi * 104) * RTRI;
    const float* cb = adc + (size_t)(qj * 104) * RTRI;

    f32x4 acc[4][2] = {};
    for (int ck = 0; ck < CHB; ++ck) {
        int k0 = (ns * CHB + ck) * DKD;
        #pragma unroll
        for (int it = 0; it < 4; ++it) {
            int idx = tid + it * 512;
            int arr = idx >> 10;
            int r = (idx >> 3) & 127;
            int kq = (idx & 7) << 2;
            const float* src = arr ? cb : qb;
            int real = arr ? realB : realA;
            float4 v = make_float4(0.f, 0.f, 0.f, 0.f);
            if (r < real) v = *(const float4*)&src[(size_t)r * RTRI + k0 + kq];
            uint2 u = make_uint2(bf2(v.x, v.y), bf2(v.z, v.w));
            unsigned short* dst = arr ? Bs : As;
            *(uint2*)&dst[r * LDK + kq] = u;
        }
        __syncthreads();
        int kb = (lane >> 4) * 8;
        bf16x8 af[4], bfv[2];
        #pragma unroll
        for (int tr = 0; tr < 4; ++tr)
            af[tr] = *(const bf16x8*)&As[(wr * 64 + tr * 16 + (lane & 15)) * LDK + kb];
        #pragma unroll
        for (int tc = 0; tc < 2; ++tc)
            bfv[tc] = *(const bf16x8*)&Bs[(wc * 32 + tc * 16 + (lane & 15)) * LDK + kb];
        #pragma unroll
        for (int tr = 0; tr < 4; ++tr)
            #pragma unroll
            for (int tc = 0; tc < 2; ++tc)
                acc[tr][tc] = __builtin_amdgcn_mfma_f32_16x16x32_bf16(
                    af[tr], bfv[tc], acc[tr][tc], 0, 0, 0);
        __syncthreads();
    }
    #pragma unroll
    for (int tr = 0; tr < 4; ++tr)
        #pragma unroll
        for (int tc = 0; tc < 2; ++tc)
            #pragma unroll
            for (int rg = 0; rg < 4; ++rg) {
                int lr = wr * 64 + tr * 16 + (lane >> 4) * 4 + rg;
                int lc = wc * 32 + tc * 16 + (lane & 15);
                if (lr < realA && lc < realB)
                    atomicAdd(&ws[WS_DOTS + (qi * 104 + lr) * 200 + (qj * 104 + lc)],
                              acc[tr][tc][rg]);
            }
}

// k5b: partial within-class ctx pair dots -> PNP[o][15], split-K
__global__ __launch_bounds__(256) void k_pn(const int* __restrict__ labels,
                                            const float* __restrict__ out,
                                            float* __restrict__ ws) {
    int o = blockIdx.x;
    int sp = blockIdx.y;
    int c = o >> 3, f = o & 7;
    int tid = threadIdx.x;
    __shared__ int rows[5];
    if (tid == 0) {
        int cnt = 0;
        for (int s = 0; s < 25; s++)
            if (labels[s] == c && cnt < 5) rows[cnt++] = s * 8 + f;
    }
    __syncthreads();
    const float* adc = out + OUT_ADC;
    float acc[15] = {};
    int lo = sp * 9240, hi = lo + 9240;
    for (int k = lo + tid; k < hi; k += 256) {
        float v[5];
        #pragma unroll
        for (int a = 0; a < 5; a++) v[a] = adc[(size_t)rows[a] * RTRI + k];
        int idx = 0;
        #pragma unroll
        for (int a = 0; a < 5; a++)
            #pragma unroll
            for (int b2 = a; b2 < 5; b2++) {
                acc[idx] = fmaf(v[a], v[b2], acc[idx]);
                idx++;
            }
    }
    __shared__ float red[15];
    if (tid < 15) red[tid] = 0.f;
    __syncthreads();
    #pragma unroll
    for (int i = 0; i < 15; i++) {
        float t = wave_reduce(acc[i]);
        if (!(tid & 63)) atomicAdd(&red[i], t);
    }
    __syncthreads();
    if (tid < 15) atomicAdd(&ws[WS_PNP + o * 16 + tid], red[tid]);
}

// k6: qn + pn finalize + ad from DOTS/PNP/QPART
__global__ __launch_bounds__(256) void k_post(const int* __restrict__ labels,
                                              float* __restrict__ ws) {
    __shared__ int mem[5][5];
    int tid = threadIdx.x;
    if (tid == 0) {
        int cnt[5] = {0,0,0,0,0};
        for (int s = 0; s < 25; s++) { int c = labels[s]; if (cnt[c] < 5) mem[c][cnt[c]++] = s; }
    }
    __syncthreads();
    for (int r = tid; r < 200; r += 256) {
        float ssum = 0.f;
        #pragma unroll
        for (int k = 0; k < 8; k++) ssum += ws[WS_QPART + (200 + r) * 8 + k];
        ws[WS_QN + r] = fmaxf(sqrtf(fmaxf(ssum, 0.f)), 1e-8f);
    }
    if (tid < 40) {
        float tot = 0.f;
        int idx = 0;
        #pragma unroll
        for (int a = 0; a < 5; a++)
            #pragma unroll
            for (int b2 = a; b2 < 5; b2++) {
                tot += ((a == b2) ? 1.f : 2.f) * ws[WS_PNP + tid * 16 + idx];
                idx++;
            }
        ws[WS_PN + tid] = fmaxf(sqrtf(fmaxf(tot, 0.f)) * 0.2f, 1e-8f);
    }
    __syncthreads();
    for (int idx = tid; idx < 8000; idx += 256) {
        int r = idx / 40, o = idx % 40;
        int c = o >> 3, f = o & 7;
        float s = 0.f;
        #pragma unroll
        for (int a = 0; a < 5; a++)
            s += ws[WS_DOTS + r * 200 + mem[c][a] * 8 + f];
        ws[WS_AD + idx] = s * 0.2f;
    }
}

// k7a: tsv[d] = sum over 200 support cls rows (atomic partials)
__global__ __launch_bounds__(384) void k_tsv(const float* __restrict__ lsn,
                                             float* __restrict__ ws) {
    int r = blockIdx.x;
    int tid = threadIdx.x;
    float s = 0.f;
    #pragma unroll
    for (int f = 0; f < 8; f++)
        s += lsn[(size_t)(r * 8 + f) * 197 * DIM + tid];
    atomicAdd(&ws[WS_TSV + tid], s);
}

// k7b: proto[q] = mean_f(query cls) + tsv/200
__global__ __launch_bounds__(384) void k_proto(const float* __restrict__ lsn,
                                               float* __restrict__ ws) {
    int q = blockIdx.x;
    int tid = threadIdx.x;
    float s = 0.f;
    #pragma unroll
    for (int f = 0; f < 8; f++)
        s += lsn[(size_t)(200 + q * 8 + f) * 197 * DIM + tid];
    ws[WS_PROTO + q * DIM + tid] = s * (1.0f / 8.0f) + ws[WS_TSV + tid] * (1.0f / 200.0f);
}

// k8: tsm[q][g] = proto[q] . gen_weight[g]
__global__ __launch_bounds__(64) void k_tsm(const float* __restrict__ gw,
                                            float* __restrict__ ws) {
    int q = blockIdx.x, g = threadIdx.x;
    const float* pr = ws + WS_PROTO + q * DIM;
    const float* gr = gw + g * DIM;
    float s = 0.f;
    for (int d = 0; d < DIM; d++) s = fmaf(pr[d], gr[d], s);
    ws[WS_TSM + q * 64 + g] = s;
}

// k9: final score
__global__ __launch_bounds__(128) void k_score(const float* __restrict__ ws,
                                               float* __restrict__ out) {
    int t = threadIdx.x;
    if (t >= 125) return;
    int q = t / 5, wway = t % 5;
    float s = 0.f;
    for (int f = 0; f < 8; f++) {
        float qn = ws[WS_QN + q * 8 + f];
        for (int g = 0; g < 8; g++) {
            float ad = ws[WS_AD + (q * 8 + f) * 40 + wway * 8 + g];
            float pnv = ws[WS_PN + wway * 8 + g];
            s += (ad / (qn * pnv)) * ws[WS_TSM + q * 64 + f * 8 + g];
        }
    }
    out[OUT_SCORE + t] = s;
}

extern "C" void kernel_launch(void* const* d_in, const int* in_sizes, int n_in,
                              void* d_out, int out_size, void* d_ws, size_t ws_size,
                              hipStream_t stream) {
    const float* lsn = (const float*)d_in[0];
    const float* gw = (const float*)d_in[1];
    const int* labels = (const int*)d_in[2];
    float* ws = (float*)d_ws;
    float* out = (float*)d_out;

    // zero only the accumulated regions: RSUM, and DOTS..AD (DOTS,PNP,TSV)
    {
        int n1 = WS_RM - WS_RSUM;      // 153600
        k_zero<<<dim3((n1 + 255) / 256), dim3(256), 0, stream>>>(ws + WS_RSUM, n1);
        int n2 = WS_AD - WS_DOTS;      // 41024
        k_zero<<<dim3((n2 + 255) / 256), dim3(256), 0, stream>>>(ws + WS_DOTS, n2);
    }
    k_prep<<<dim3(BATCH), dim3(384), 0, stream>>>(lsn, ws, out);
    k_gram<<<dim3(21 * BATCH), dim3(256), 0, stream>>>(lsn, ws, out);
    k_rowmean<<<dim3(BATCH), dim3(384), 0, stream>>>(ws);
    k_center<<<dim3(8, BATCH), dim3(256), 0, stream>>>(ws, out);
    k_dots<<<dim3(2, 2, NS2), dim3(512), 0, stream>>>(out, ws);
    k_pn<<<dim3(40, 8), dim3(256), 0, stream>>>(labels, out, ws);
    k_tsv<<<dim3(25), dim3(384), 0, stream>>>(lsn, ws);
    k_proto<<<dim3(25), dim3(384), 0, stream>>>(lsn, ws);
    k_post<<<1, dim3(256), 0, stream>>>(labels, ws);
    k_tsm<<<dim3(25), dim3(64), 0, stream>>>(gw, ws);
    k_score<<<1, dim3(128), 0, stream>>>(ws, out);
}

// Round 19
// 328.319 us; speedup vs baseline: 1.3958x; 1.0344x over previous
//
#include <hip/hip_runtime.h>
#include <hip/hip_bf16.h>

#define BATCH 400
#define NPATCH 196
#define DIM 384
#define RTRI 73920          // 384*385/2
#define NSUP 200
#define OUT_SCORE 0
#define OUT_ADC 125
#define OUT_CLS (125 + BATCH * RTRI)

// ws offsets in floats
#define WS_W      0         // 400*196  (holds w)
#define WS_SQ     78400     // 400*384
#define WS_RSUM   232000    // 400*384 (atomic; zeroed each launch)
#define WS_QPART  539600    // 400*8   (plain-written)
#define WS_DOTS   542800    // 200*200 (atomic; zeroed)
#define WS_PNP    582800    // 40*16 (atomic; zeroed)
#define WS_TSV    583440    // 384 (atomic; zeroed)
#define WS_AD     583824    // 200*40
#define WS_QN     591824    // 200
#define WS_PN     592024    // 40
#define WS_TSM    601664    // 25*64
#define WS_TOTAL  603264

typedef __attribute__((ext_vector_type(8))) short bf16x8;
typedef __attribute__((ext_vector_type(4))) short short4v;
typedef __attribute__((ext_vector_type(4))) float f32x4;

__device__ __forceinline__ float wave_reduce(float v) {
    #pragma unroll
    for (int o = 32; o; o >>= 1) v += __shfl_down(v, o);
    return v;
}

__device__ __forceinline__ float wave_allreduce(float v) {
    #pragma unroll
    for (int o = 1; o < 64; o <<= 1) v += __shfl_xor(v, o);
    return v;
}

// native bf16 conversions, RNE
__device__ __forceinline__ unsigned short bf1(float x) {
    __hip_bfloat16 h = __float2bfloat16(x);
    unsigned short u;
    __builtin_memcpy(&u, &h, 2);
    return u;
}
__device__ __forceinline__ unsigned int bf2(float x, float y) {
    __hip_bfloat162 h = __float22bfloat162_rn(make_float2(x, y));
    unsigned int u;
    __builtin_memcpy(&u, &h, 4);
    return u;
}

// zero both atomic regions in one launch
#define ZN1 (WS_QPART - WS_RSUM)       // 307600 - wait, RSUM..QPART region
#define ZR1 153600                      // RSUM size (400*384)
#define ZR2 (WS_AD - WS_DOTS)           // DOTS,PNP,TSV = 41024
__global__ void k_zero2(float* __restrict__ ws) {
    int i = blockIdx.x * 256 + threadIdx.x;
    if (i < ZR1) ws[WS_RSUM + i] = 0.f;
    else if (i < ZR1 + ZR2) ws[WS_DOTS + (i - ZR1)] = 0.f;
}

// k1: cosine weights w (stored raw), cls fp32 copy, sq[d] fused (single pass)
__global__ __launch_bounds__(384) void k_prep(const float* __restrict__ lsn,
                                              float* __restrict__ ws,
                                              float* __restrict__ out) {
    int b = blockIdx.x, tid = threadIdx.x;
    __shared__ float clsL[DIM];
    __shared__ float red[6];
    __shared__ float sqP[6][DIM];
    const float* base = lsn + (size_t)b * 197 * DIM;
    float c = base[tid];
    clsL[tid] = c;
    out[OUT_CLS + (size_t)b * DIM + tid] = c;
    float s = wave_reduce(c * c);
    int lane = tid & 63, wv = tid >> 6;
    if (!lane) red[wv] = s;
    __syncthreads();
    float clsn = fmaxf(sqrtf(red[0]+red[1]+red[2]+red[3]+red[4]+red[5]), 1e-8f);
    const float* patch = base + DIM;
    float acc6[6] = {0.f, 0.f, 0.f, 0.f, 0.f, 0.f};
    for (int p = wv; p < NPATCH; p += 6) {
        const float* pr = patch + p * DIM;
        float v[6];
        float dot = 0.f, nsq = 0.f;
        #pragma unroll
        for (int t = 0; t < 6; t++) {
            v[t] = pr[lane + 64 * t];
            dot = fmaf(v[t], clsL[lane + 64 * t], dot);
            nsq = fmaf(v[t], v[t], nsq);
        }
        dot = wave_allreduce(dot);
        nsq = wave_allreduce(nsq);
        float w = dot / (clsn * fmaxf(sqrtf(nsq), 1e-8f));
        if (!lane) ws[WS_W + b * NPATCH + p] = w;
        #pragma unroll
        for (int t = 0; t < 6; t++) {
            float wv_ = w * v[t];
            acc6[t] = fmaf(wv_, wv_, acc6[t]);
        }
    }
    #pragma unroll
    for (int t = 0; t < 6; t++) sqP[wv][lane + 64 * t] = acc6[t];
    __syncthreads();
    float tot = 0.f;
    #pragma unroll
    for (int w6 = 0; w6 < 6; w6++) tot += sqP[w6][tid];
    ws[WS_SQ + b * DIM + tid] = tot * (1.0f / 392.0f);
}

// k2: bf16 MFMA Gram (r18-converged structure, unchanged)
#define GLDM 232
__global__ __launch_bounds__(256) void k_gram(const float* __restrict__ lsn,
                                              float* __restrict__ ws,
                                              float* __restrict__ out) {
    int bx = blockIdx.x;
    int xcd = bx & 7;
    int slot = bx >> 3;
    int t = slot % 21;
    int b = (slot / 21) * 8 + xcd;

    int ti = 0;
    {
        int tt = t;
        while (tt >= 6 - ti) { tt -= 6 - ti; ++ti; }
        t = ti + tt;
    }
    int tj = t;
    bool diag = (ti == tj);

    __shared__ __align__(16) unsigned short As[64 * GLDM];
    __shared__ __align__(16) unsigned short Bs[64 * GLDM];
    __shared__ float wL[224];

    int tid = threadIdx.x;
    int lane = tid & 63, w = tid >> 6;
    int wr = w >> 1, wc = w & 1;
    int dl = lane & 15, ms4 = lane >> 4;

    const float* patch = lsn + (size_t)b * 197 * DIM + DIM;
    const float* wrow = ws + WS_W + b * NPATCH;

    if (tid < 224) wL[tid] = (tid < NPATCH) ? wrow[tid] : 0.f;
    __syncthreads();

    int col2 = tid & 15;
    int mrow = tid >> 4;
    int c4 = col2 << 2;
    int blow = mrow & 7;
    int ahi = mrow >> 3;

    #pragma unroll
    for (int arr = 0; arr < 2; ++arr) {
        if (arr && diag) break;
        unsigned short* dst = arr ? Bs : As;
        const float* srcbase = patch + (arr ? tj : ti) * 64 + c4;
        int g2 = ahi + col2;
        #pragma unroll
        for (int itm = 0; itm < 14; ++itm) {
            int m = mrow + itm * 16;
            float4 v = make_float4(0.f, 0.f, 0.f, 0.f);
            if (m < NPATCH) v = *(const float4*)&srcbase[(size_t)m * DIM];
            float wm = wL[m];
            v.x *= wm; v.y *= wm; v.z *= wm; v.w *= wm;
            int rowoff = g2 * 8 + blow;
            dst[(c4 + 0) * GLDM + rowoff] = bf1(v.x);
            dst[(c4 + 1) * GLDM + rowoff] = bf1(v.y);
            dst[(c4 + 2) * GLDM + rowoff] = bf1(v.z);
            dst[(c4 + 3) * GLDM + rowoff] = bf1(v.w);
            g2 += 2;
            if (g2 >= 29) g2 -= 29;
        }
    }
    __syncthreads();

    const unsigned short* Bbase = diag ? As : Bs;
    f32x4 acc[2][2] = {};
    for (int ks = 0; ks < 7; ++ks) {
        bf16x8 af[2], bfv[2];
        #pragma unroll
        for (int tr = 0; tr < 2; ++tr) {
            int colA = wr * 32 + tr * 16 + dl;
            int gg = ks * 4 + ms4 + (colA >> 2);
            if (gg >= 29) gg -= 29;
            af[tr] = *(const bf16x8*)&As[colA * GLDM + gg * 8];
        }
        #pragma unroll
        for (int tc = 0; tc < 2; ++tc) {
            int colB = wc * 32 + tc * 16 + dl;
            int gg = ks * 4 + ms4 + (colB >> 2);
            if (gg >= 29) gg -= 29;
            bfv[tc] = *(const bf16x8*)&Bbase[colB * GLDM + gg * 8];
        }
        #pragma unroll
        for (int tr = 0; tr < 2; ++tr)
            #pragma unroll
            for (int tc = 0; tc < 2; ++tc)
                acc[tr][tc] = __builtin_amdgcn_mfma_f32_16x16x32_bf16(
                    af[tr], bfv[tc], acc[tr][tc], 0, 0, 0);
    }

    const float* sqb = ws + WS_SQ + b * DIM;
    int rbase = ti * 64 + wr * 32;
    int cbase = tj * 64 + wc * 32;
    float sqi[2][4], sqj[2];
    #pragma unroll
    for (int tr = 0; tr < 2; ++tr)
        #pragma unroll
        for (int rg = 0; rg < 4; ++rg)
            sqi[tr][rg] = sqb[rbase + tr * 16 + ms4 * 4 + rg];
    #pragma unroll
    for (int tc = 0; tc < 2; ++tc)
        sqj[tc] = sqb[cbase + tc * 16 + dl];

    float* adc = out + OUT_ADC + (size_t)b * RTRI;
    float rs[2][4] = {};
    float cs[2] = {0.f, 0.f};
    #pragma unroll
    for (int tr = 0; tr < 2; ++tr) {
        #pragma unroll
        for (int rg = 0; rg < 4; ++rg) {
            int gi = rbase + tr * 16 + ms4 * 4 + rg;
            int goff = gi * (769 - gi) / 2 - gi;
            float sq_i = sqi[tr][rg];
            float rsv = 0.f;
            #pragma unroll
            for (int tc = 0; tc < 2; ++tc) {
                int gj = cbase + tc * 16 + dl;
                float dc = sq_i + sqj[tc] - acc[tr][tc][rg] * (1.0f / 196.0f);
                if (gi == gj) dc = 0.f;
                dc = fmaxf(dc, 0.f) + 1e-5f;
                float val = __expf(0.4f * __logf(dc));
                rsv += val;
                cs[tc] += val;
                if (gj >= gi)
                    adc[goff + gj] = val;
            }
            rs[tr][rg] = rsv;
        }
    }
    #pragma unroll
    for (int tr = 0; tr < 2; ++tr)
        #pragma unroll
        for (int rg = 0; rg < 4; ++rg) {
            float vv = rs[tr][rg];
            vv += __shfl_xor(vv, 1); vv += __shfl_xor(vv, 2);
            vv += __shfl_xor(vv, 4); vv += __shfl_xor(vv, 8);
            rs[tr][rg] = vv;
        }
    if ((lane & 15) == 0) {
        #pragma unroll
        for (int tr = 0; tr < 2; ++tr)
            #pragma unroll
            for (int rg = 0; rg < 4; ++rg)
                atomicAdd(&ws[WS_RSUM + b * DIM + rbase + tr * 16 + ms4 * 4 + rg],
                          rs[tr][rg]);
    }
    if (ti != tj) {
        #pragma unroll
        for (int tc = 0; tc < 2; ++tc) {
            float vv = cs[tc];
            vv += __shfl_xor(vv, 16); vv += __shfl_xor(vv, 32);
            cs[tc] = vv;
        }
        if (lane < 16) {
            #pragma unroll
            for (int tc = 0; tc < 2; ++tc)
                atomicAdd(&ws[WS_RSUM + b * DIM + cbase + tc * 16 + lane], cs[tc]);
        }
    }
}

// k4: centering, rm/gm computed inline from RSUM (k_rowmean folded in)
__global__ __launch_bounds__(256) void k_center(float* __restrict__ ws,
                                                float* __restrict__ out) {
    int s = blockIdx.x;       // 0..7
    int b = blockIdx.y;
    int tid = threadIdx.x;
    int lane = tid & 63, wv = tid >> 6;
    __shared__ float rmL[DIM];
    __shared__ float redL[4];
    const float* rsum = ws + WS_RSUM + b * DIM;
    float r0 = rsum[tid] * (1.0f / 384.0f);
    rmL[tid] = r0;
    float r1 = 0.f;
    if (tid < DIM - 256) {
        r1 = rsum[256 + tid] * (1.0f / 384.0f);
        rmL[256 + tid] = r1;
    }
    float pt = wave_reduce(r0 + r1);
    if (!lane) redL[wv] = pt;
    __syncthreads();
    float gm = (redL[0] + redL[1] + redL[2] + redL[3]) * (1.0f / 384.0f);
    __syncthreads();          // protect redL reuse below
    float* adc = out + OUT_ADC + (size_t)b * RTRI;
    float acc = 0.f;
    int slot = s * 4 + wv;               // 0..31
    for (int k = 0; k < 12; ++k) {
        int i = slot + 32 * k;           // 0..383
        int base = i * (769 - i) / 2;
        int L = DIM - i;
        float rmi = rmL[i] - gm;
        int head = (4 - ((125 + base) & 3)) & 3;
        if (head > L) head = L;
        if (lane < head) {
            float v = adc[base + lane];
            float nv = v - rmi - rmL[i + lane];
            adc[base + lane] = nv;
            acc = fmaf(nv, nv, acc);
        }
        int n4 = (L - head) >> 2;
        for (int q = lane; q < n4; q += 64) {
            int off = head + q * 4;
            float4 v = *(float4*)&adc[base + off];
            float nv0 = v.x - rmi - rmL[i + off];
            float nv1 = v.y - rmi - rmL[i + off + 1];
            float nv2 = v.z - rmi - rmL[i + off + 2];
            float nv3 = v.w - rmi - rmL[i + off + 3];
            *(float4*)&adc[base + off] = make_float4(nv0, nv1, nv2, nv3);
            acc = fmaf(nv0, nv0, acc);
            acc = fmaf(nv1, nv1, acc);
            acc = fmaf(nv2, nv2, acc);
            acc = fmaf(nv3, nv3, acc);
        }
        int tl = head + n4 * 4 + lane;
        if (tl < L) {
            float v = adc[base + tl];
            float nv = v - rmi - rmL[i + tl];
            adc[base + tl] = nv;
            acc = fmaf(nv, nv, acc);
        }
    }
    float t = wave_reduce(acc);
    if (!lane) redL[wv] = t;
    __syncthreads();
    if (!tid) ws[WS_QPART + b * 8 + s] = redL[0] + redL[1] + redL[2] + redL[3];
}

// k5: DOTS via split-K bf16 MFMA (unchanged)
#define DKD 32
#define LDK 40
#define NS2 105
#define CHB 22
__global__ __launch_bounds__(512) void k_dots(const float* __restrict__ out,
                                              float* __restrict__ ws) {
    int qi = blockIdx.x, qj = blockIdx.y, ns = blockIdx.z;
    int tid = threadIdx.x;
    int lane = tid & 63, w = tid >> 6;
    int wr = w >> 2, wc = w & 3;
    __shared__ __align__(16) unsigned short As[128 * LDK];
    __shared__ __align__(16) unsigned short Bs[128 * LDK];
    const float* adc = out + OUT_ADC;
    int realA = (qi == 0) ? 104 : 96;
    int realB = (qj == 0) ? 104 : 96;
    const float* qb = adc + (size_t)(NSUP + qi * 104) * RTRI;
    const float* cb = adc + (size_t)(qj * 104) * RTRI;

    f32x4 acc[4][2] = {};
    for (int ck = 0; ck < CHB; ++ck) {
        int k0 = (ns * CHB + ck) * DKD;
        #pragma unroll
        for (int it = 0; it < 4; ++it) {
            int idx = tid + it * 512;
            int arr = idx >> 10;
            int r = (idx >> 3) & 127;
            int kq = (idx & 7) << 2;
            const float* src = arr ? cb : qb;
            int real = arr ? realB : realA;
            float4 v = make_float4(0.f, 0.f, 0.f, 0.f);
            if (r < real) v = *(const float4*)&src[(size_t)r * RTRI + k0 + kq];
            uint2 u = make_uint2(bf2(v.x, v.y), bf2(v.z, v.w));
            unsigned short* dst = arr ? Bs : As;
            *(uint2*)&dst[r * LDK + kq] = u;
        }
        __syncthreads();
        int kb = (lane >> 4) * 8;
        bf16x8 af[4], bfv[2];
        #pragma unroll
        for (int tr = 0; tr < 4; ++tr)
            af[tr] = *(const bf16x8*)&As[(wr * 64 + tr * 16 + (lane & 15)) * LDK + kb];
        #pragma unroll
        for (int tc = 0; tc < 2; ++tc)
            bfv[tc] = *(const bf16x8*)&Bs[(wc * 32 + tc * 16 + (lane & 15)) * LDK + kb];
        #pragma unroll
        for (int tr = 0; tr < 4; ++tr)
            #pragma unroll
            for (int tc = 0; tc < 2; ++tc)
                acc[tr][tc] = __builtin_amdgcn_mfma_f32_16x16x32_bf16(
                    af[tr], bfv[tc], acc[tr][tc], 0, 0, 0);
        __syncthreads();
    }
    #pragma unroll
    for (int tr = 0; tr < 4; ++tr)
        #pragma unroll
        for (int tc = 0; tc < 2; ++tc)
            #pragma unroll
            for (int rg = 0; rg < 4; ++rg) {
                int lr = wr * 64 + tr * 16 + (lane >> 4) * 4 + rg;
                int lc = wc * 32 + tc * 16 + (lane & 15);
                if (lr < realA && lc < realB)
                    atomicAdd(&ws[WS_DOTS + (qi * 104 + lr) * 200 + (qj * 104 + lc)],
                              acc[tr][tc][rg]);
            }
}

// k5b: partial within-class ctx pair dots -> PNP[o][15], split-K
__global__ __launch_bounds__(256) void k_pn(const int* __restrict__ labels,
                                            const float* __restrict__ out,
                                            float* __restrict__ ws) {
    int o = blockIdx.x;
    int sp = blockIdx.y;
    int c = o >> 3, f = o & 7;
    int tid = threadIdx.x;
    __shared__ int rows[5];
    if (tid == 0) {
        int cnt = 0;
        for (int s = 0; s < 25; s++)
            if (labels[s] == c && cnt < 5) rows[cnt++] = s * 8 + f;
    }
    __syncthreads();
    const float* adc = out + OUT_ADC;
    float acc[15] = {};
    int lo = sp * 9240, hi = lo + 9240;
    for (int k = lo + tid; k < hi; k += 256) {
        float v[5];
        #pragma unroll
        for (int a = 0; a < 5; a++) v[a] = adc[(size_t)rows[a] * RTRI + k];
        int idx = 0;
        #pragma unroll
        for (int a = 0; a < 5; a++)
            #pragma unroll
            for (int b2 = a; b2 < 5; b2++) {
                acc[idx] = fmaf(v[a], v[b2], acc[idx]);
                idx++;
            }
    }
    __shared__ float red[15];
    if (tid < 15) red[tid] = 0.f;
    __syncthreads();
    #pragma unroll
    for (int i = 0; i < 15; i++) {
        float t = wave_reduce(acc[i]);
        if (!(tid & 63)) atomicAdd(&red[i], t);
    }
    __syncthreads();
    if (tid < 15) atomicAdd(&ws[WS_PNP + o * 16 + tid], red[tid]);
}

// k7a: tsv[d] = sum over 200 support cls rows (atomic partials)
__global__ __launch_bounds__(384) void k_tsv(const float* __restrict__ lsn,
                                             float* __restrict__ ws) {
    int r = blockIdx.x;
    int tid = threadIdx.x;
    float s = 0.f;
    #pragma unroll
    for (int f = 0; f < 8; f++)
        s += lsn[(size_t)(r * 8 + f) * 197 * DIM + tid];
    atomicAdd(&ws[WS_TSV + tid], s);
}

// k7b: proto (LDS only) + tsm fused
__global__ __launch_bounds__(384) void k_proto_tsm(const float* __restrict__ lsn,
                                                   const float* __restrict__ gw,
                                                   float* __restrict__ ws) {
    int q = blockIdx.x;      // 0..24
    int tid = threadIdx.x;
    __shared__ float protoL[DIM];
    __shared__ float tsp[6][64];
    float s = 0.f;
    #pragma unroll
    for (int f = 0; f < 8; f++)
        s += lsn[(size_t)(200 + q * 8 + f) * 197 * DIM + tid];
    protoL[tid] = s * (1.0f / 8.0f) + ws[WS_TSV + tid] * (1.0f / 200.0f);
    __syncthreads();
    int g = tid & 63, ch = tid >> 6;     // 64 g x 6 chunks
    const float* gr = gw + g * DIM + ch * 64;
    const float* pr = protoL + ch * 64;
    float dot = 0.f;
    #pragma unroll
    for (int d = 0; d < 64; ++d) dot = fmaf(pr[d], gr[d], dot);
    tsp[ch][g] = dot;
    __syncthreads();
    if (tid < 64)
        ws[WS_TSM + q * 64 + tid] = tsp[0][tid] + tsp[1][tid] + tsp[2][tid]
                                  + tsp[3][tid] + tsp[4][tid] + tsp[5][tid];
}

// k6+k9 fused: qn/pn/ad finalize then score
__global__ __launch_bounds__(256) void k_post_score(const int* __restrict__ labels,
                                                    float* __restrict__ ws,
                                                    float* __restrict__ out) {
    __shared__ int mem[5][5];
    int tid = threadIdx.x;
    if (tid == 0) {
        int cnt[5] = {0,0,0,0,0};
        for (int s = 0; s < 25; s++) { int c = labels[s]; if (cnt[c] < 5) mem[c][cnt[c]++] = s; }
    }
    __syncthreads();
    for (int r = tid; r < 200; r += 256) {
        float ssum = 0.f;
        #pragma unroll
        for (int k = 0; k < 8; k++) ssum += ws[WS_QPART + (200 + r) * 8 + k];
        ws[WS_QN + r] = fmaxf(sqrtf(fmaxf(ssum, 0.f)), 1e-8f);
    }
    if (tid < 40) {
        float tot = 0.f;
        int idx = 0;
        #pragma unroll
        for (int a = 0; a < 5; a++)
            #pragma unroll
            for (int b2 = a; b2 < 5; b2++) {
                tot += ((a == b2) ? 1.f : 2.f) * ws[WS_PNP + tid * 16 + idx];
                idx++;
            }
        ws[WS_PN + tid] = fmaxf(sqrtf(fmaxf(tot, 0.f)) * 0.2f, 1e-8f);
    }
    __syncthreads();
    for (int idx = tid; idx < 8000; idx += 256) {
        int r = idx / 40, o = idx % 40;
        int c = o >> 3, f = o & 7;
        float s = 0.f;
        #pragma unroll
        for (int a = 0; a < 5; a++)
            s += ws[WS_DOTS + r * 200 + mem[c][a] * 8 + f];
        ws[WS_AD + idx] = s * 0.2f;
    }
    __syncthreads();
    int t = tid;
    if (t < 125) {
        int q = t / 5, wway = t % 5;
        float s = 0.f;
        for (int f = 0; f < 8; f++) {
            float qn = ws[WS_QN + q * 8 + f];
            for (int g = 0; g < 8; g++) {
                float ad = ws[WS_AD + (q * 8 + f) * 40 + wway * 8 + g];
                float pnv = ws[WS_PN + wway * 8 + g];
                s += (ad / (qn * pnv)) * ws[WS_TSM + q * 64 + f * 8 + g];
            }
        }
        out[OUT_SCORE + t] = s;
    }
}

extern "C" void kernel_launch(void* const* d_in, const int* in_sizes, int n_in,
                              void* d_out, int out_size, void* d_ws, size_t ws_size,
                              hipStream_t stream) {
    const float* lsn = (const float*)d_in[0];
    const float* gw = (const float*)d_in[1];
    const int* labels = (const int*)d_in[2];
    float* ws = (float*)d_ws;
    float* out = (float*)d_out;

    {
        int n = ZR1 + ZR2;
        k_zero2<<<dim3((n + 255) / 256), dim3(256), 0, stream>>>(ws);
    }
    k_prep<<<dim3(BATCH), dim3(384), 0, stream>>>(lsn, ws, out);
    k_gram<<<dim3(21 * BATCH), dim3(256), 0, stream>>>(lsn, ws, out);
    k_center<<<dim3(8, BATCH), dim3(256), 0, stream>>>(ws, out);
    k_dots<<<dim3(2, 2, NS2), dim3(512), 0, stream>>>(out, ws);
    k_pn<<<dim3(40, 8), dim3(256), 0, stream>>>(labels, out, ws);
    k_tsv<<<dim3(25), dim3(384), 0, stream>>>(lsn, ws);
    k_proto_tsm<<<dim3(25), dim3(384), 0, stream>>>(lsn, gw, ws);
    k_post_score<<<1, dim3(256), 0, stream>>>(labels, ws, out);
}